// Round 6
// baseline (1604.563 us; speedup 1.0000x reference)
//
#include <hip/hip_runtime.h>
#include <hip/hip_bf16.h>
#include <math.h>

#define Hn 256
#define Wn 256
#define Cn 64
#define Mk 12
#define NM 24
#define FCH 128
#define HW 65536

using half8 = __attribute__((ext_vector_type(8))) _Float16;
using f32x4 = __attribute__((ext_vector_type(4))) float;

__device__ __forceinline__ float gelu_exact(float x) {
    return 0.5f * x * (1.0f + erff(x * 0.7071067811865476f));
}
__device__ __forceinline__ unsigned short f2h(float f) {
    _Float16 h = (_Float16)f;
    return __builtin_bit_cast(unsigned short, h);
}
__device__ __forceinline__ float h2lo(unsigned u) {
    return (float)__builtin_bit_cast(_Float16, (unsigned short)(u & 0xffffu));
}
__device__ __forceinline__ float h2hi(unsigned u) {
    return (float)__builtin_bit_cast(_Float16, (unsigned short)(u >> 16));
}

// ---------------- trig tables ----------------
__global__ __launch_bounds__(256) void k_init_tables(float* tc, float* ts,
                                                     float* twc, float* tws,
                                                     float* tcs,
                                                     unsigned short* bfr,
                                                     unsigned short* tfr) {
    int i = threadIdx.x;  // 0..255
    const float step = 0.024543692606170259f;  // 2*pi/256
    float c = cosf(i * step), s = sinf(i * step);
    tc[i] = c; ts[i] = s;
    tcs[2 * i] = c; tcs[2 * i + 1] = s;
    for (int k = 0; k < Mk; ++k) {
        int idx = (i * k) & 255;
        twc[i * Mk + k] = cosf(idx * step);
        tws[i * Mk + k] = sinf(idx * step);
    }
    for (int e = i; e < 8192; e += 256) {
        int j  = e & 7;
        int l  = (e >> 3) & 63;
        int sn = e >> 9;            // s*2+n
        int col = (sn & 1) * 16 + (l & 15);
        int ky = col >> 1, p = col & 1;
        int k  = (sn >> 1) * 32 + ((l >> 4) & 3) * 8 + j;
        int idx = (ky * k) & 255;
        float v = p ? -sinf(idx * step) : cosf(idx * step);
        bfr[e] = f2h(v);
    }
    for (int e = i; e < 12288; e += 256) {
        int j  = e & 7;
        int l  = (e >> 3) & 63;
        int sm = e >> 9;            // s*3+mt
        int mt = sm % 3, s2 = sm / 3;
        int r  = mt * 16 + (l & 15);
        int hh = s2 * 32 + ((l >> 4) & 3) * 8 + j;
        int m  = (r < 24) ? r : (r - 24);
        int kx = (m < Mk) ? m : (232 + m);
        int idx = (kx * hh) & 255;
        float v = (r < 24) ? cosf(idx * step) : sinf(idx * step);
        tfr[e] = f2h(v);
    }
}

// ---- weight/twiddle fragment tables for fusedA/fusedB ----
__global__ __launch_bounds__(256) void k_prep_frag(const float* __restrict__ pww,
                                                   const float* __restrict__ fc1w,
                                                   unsigned short* __restrict__ efr,
                                                   unsigned short* __restrict__ pwfr,
                                                   unsigned short* __restrict__ fc1fr) {
    int e = blockIdx.x * 256 + threadIdx.x;   // < 32768
    const float step = 0.024543692606170259f;
    int j = e & 7, l = (e >> 3) & 63;
    int row = l & 15;
    int k = ((l >> 4) & 3) * 8 + j;
    if (e < 8192) {
        int mt = (e >> 9) & 15;
        int pix = mt * 16 + row;
        float v = 0.f;
        if (k < 12) v = cosf(((k * pix) & 255) * step);
        else if (k < 24) v = -sinf((((k - 12) * pix) & 255) * step);
        efr[e] = f2h(v);
    } else if (e < 24576) {
        int e2 = e - 8192;
        int nt = (e2 >> 9) & 3;
        int ks = (e2 >> 11) & 1;
        int l4 = e2 >> 12;
        int o = nt * 16 + row;
        int i = ks * 32 + k;
        pwfr[e2] = f2h(pww[(size_t)(l4 * 64 + o) * 64 + i]);
    } else {
        int e2 = e - 24576;
        int nt = (e2 >> 9) & 7;
        int ks = (e2 >> 12) & 1;
        int d = nt * 16 + row;
        int i = ks * 32 + k;
        fc1fr[e2] = f2h(fc1w[i * 128 + d]);
    }
}

// ------- spectral weight transpose: scw[l,j,i,o,kx,ky,2] -> scwT[l,j,kx,ky,i,o,2]
__global__ __launch_bounds__(256) void k_prep_w(const float* __restrict__ scw,
                                                float* __restrict__ scwT) {
    int t = blockIdx.x * 256 + threadIdx.x;  // < 2,359,296
    int o  = t & 63;
    int i  = (t >> 6) & 63;
    int r  = t >> 12;
    int u  = r % 6;
    int kx = (r / 6) % 12;
    int lj = r / 72;
    int ky = 2 * u;
    size_t in_idx = ((((size_t)lj * 64 + i) * 64 + o) * 144) + kx * Mk + ky;
    float4 v = *(const float4*)(scw + 2 * in_idx);
    size_t o0 = ((((size_t)(lj * 12 + kx) * Mk + ky) * 64 + i) * 64 + o);
    size_t o1 = ((((size_t)(lj * 12 + kx) * Mk + ky + 1) * 64 + i) * 64 + o);
    *(float2*)(scwT + 2 * o0) = make_float2(v.x, v.y);
    *(float2*)(scwT + 2 * o1) = make_float2(v.z, v.w);
}

// ------- expand scwT -> wfr: per matrix (lj,kxw,ky) a 128x128 fp16 B-frag -------
// B[k=2i+p][col=2o+pp]: (p,pp)=(0,0):wr (0,1):wi (1,0):-wi (1,1):wr
// frag layout [mat1152][s4][nt8][lane64][j8] fp16
__global__ __launch_bounds__(256) void k_prep_wfrag(const float* __restrict__ scwT,
                                                    unsigned short* __restrict__ wfr) {
    __shared__ float Ws[8192];
    int mat = blockIdx.x;            // lj*144 + kxw*12 + ky
    int t = threadIdx.x;
    const float4* src = (const float4*)(scwT + (size_t)mat * 8192);
#pragma unroll
    for (int r = 0; r < 8; ++r)
        ((float4*)Ws)[r * 256 + t] = src[r * 256 + t];
    __syncthreads();
    unsigned short* dst = wfr + (size_t)mat * 16384;
#pragma unroll
    for (int u = 0; u < 8; ++u) {
        int lin = u * 256 + t;                 // (s*8+nt)*64 + lane
        int lane = lin & 63, nt = (lin >> 6) & 7, s = lin >> 9;
        int col = nt * 16 + (lane & 15);
        int o = col >> 1, pp = col & 1;
        int tg = (lane >> 4) & 3;
        unsigned pk[4];
#pragma unroll
        for (int jp = 0; jp < 4; ++jp) {
            unsigned short hv[2];
#pragma unroll
            for (int hz = 0; hz < 2; ++hz) {
                int k = s * 32 + tg * 8 + jp * 2 + hz;
                int i = k >> 1, p = k & 1;
                float wr_ = Ws[(i * 64 + o) * 2];
                float wi_ = Ws[(i * 64 + o) * 2 + 1];
                float v = (p == 0) ? (pp == 0 ? wr_ : wi_)
                                   : (pp == 0 ? -wi_ : wr_);
                hv[hz] = f2h(v);
            }
            pk[jp] = hv[0] | ((unsigned)hv[1] << 16);
        }
        uint4 w4 = {pk[0], pk[1], pk[2], pk[3]};
        *(uint4*)(dst + lin * 8) = w4;
    }
}

// ------- DFT along W of x -------
__global__ __launch_bounds__(64) void k_dftw_x(const float* __restrict__ x,
                                               float* __restrict__ Xxw,
                                               const float* __restrict__ twc,
                                               const float* __restrict__ tws) {
    int r = blockIdx.x * 64 + threadIdx.x;
    const float* hp = x + (size_t)r * Wn;
    float xr[Mk], xi[Mk];
#pragma unroll
    for (int k = 0; k < Mk; ++k) { xr[k] = 0.f; xi[k] = 0.f; }
    for (int w4 = 0; w4 < 64; ++w4) {
        float4 v = ((const float4*)hp)[w4];
        float vv[4] = {v.x, v.y, v.z, v.w};
#pragma unroll
        for (int j = 0; j < 4; ++j) {
            int wbase = (w4 * 4 + j) * Mk;
#pragma unroll
            for (int k = 0; k < Mk; ++k) {
                xr[k] += vv[j] * twc[wbase + k];
                xi[k] -= vv[j] * tws[wbase + k];
            }
        }
    }
    float* op = Xxw + (size_t)r * (2 * Mk);
#pragma unroll
    for (int k = 0; k < Mk; ++k) { op[2 * k] = xr[k]; op[2 * k + 1] = xi[k]; }
}

// ------- DFT along H of x-modes -> Xfx[b][m][ky] -------
__global__ __launch_bounds__(256) void k_xdfth(const float* __restrict__ Xxw,
                                               float* __restrict__ Xfx,
                                               const float* __restrict__ tc,
                                               const float* __restrict__ ts) {
    int t = blockIdx.x * 256 + threadIdx.x;
    if (t >= 16 * 288) return;
    int ky = t % Mk;
    int m  = (t / Mk) % NM;
    int b  = t / 288;
    int kx = (m < Mk) ? m : (232 + m);
    const float* base = Xxw + (size_t)b * Hn * 2 * Mk + 2 * ky;
    float ar = 0.f, ai = 0.f;
    for (int hh = 0; hh < Hn; ++hh) {
        float vr = base[hh * 2 * Mk];
        float vi = base[hh * 2 * Mk + 1];
        int idx = (kx * hh) & 255;
        float c = tc[idx], s = ts[idx];
        ar += vr * c + vi * s;
        ai += vi * c - vr * s;
    }
    Xfx[2 * t] = ar;
    Xfx[2 * t + 1] = ai;
}

// ------- mode mix via MFMA (all layers; l=0 folds the lift) -------
// block = jj*144 + kxw*12 + ky; C[b16][2o+pp] = A[b][2i+p]/16 @ Wexp
__global__ __launch_bounds__(256) void k_mixZ2(const float* __restrict__ xin,
                                               const unsigned short* __restrict__ wfr,
                                               const float* __restrict__ w0,
                                               const float* __restrict__ b0v,
                                               float* __restrict__ Z,
                                               int l, int first, int b0, int bc) {
    __shared__ __align__(16) char smem[4096];
    int t = threadIdx.x;
    int lane = t & 63, q = t >> 6, tg = (lane >> 4) & 3;
    int blk = blockIdx.x;
    int jj = blk / 144, kxw = (blk / 12) % 12, ky = blk % 12;
    int mm = jj * 12 + kxw;
    int mk = mm * 12 + ky;
    int mat = (l * 2 + jj) * 144 + kxw * 12 + ky;
    // stage A[b][k] fp16 (scaled 1/16), XOR-swizzled rows of 256B
    {
        int b = t >> 4, c16 = t & 15;
        uint4 pk = {0u, 0u, 0u, 0u};
        if (b < bc) {
            if (first) {
                float xr = xin[((b0 + b) * 288 + mk) * 2] * 0.0625f;
                float xi = xin[((b0 + b) * 288 + mk) * 2 + 1] * 0.0625f;
                float4 wv = *(const float4*)(w0 + c16 * 4);
                float4 bv = {0.f, 0.f, 0.f, 0.f};
                if (mk == 0) {
                    float4 bb = *(const float4*)(b0v + c16 * 4);
                    bv.x = 4096.f * bb.x; bv.y = 4096.f * bb.y;
                    bv.z = 4096.f * bb.z; bv.w = 4096.f * bb.w;
                }
                pk.x = f2h(wv.x * xr + bv.x) | ((unsigned)f2h(wv.x * xi) << 16);
                pk.y = f2h(wv.y * xr + bv.y) | ((unsigned)f2h(wv.y * xi) << 16);
                pk.z = f2h(wv.z * xr + bv.z) | ((unsigned)f2h(wv.z * xi) << 16);
                pk.w = f2h(wv.w * xr + bv.w) | ((unsigned)f2h(wv.w * xi) << 16);
            } else {
                const float* src = xin + ((size_t)b * 288 + mk) * 128 + c16 * 8;
                float4 v0 = *(const float4*)(src);
                float4 v1 = *(const float4*)(src + 4);
                pk.x = f2h(v0.x * 0.0625f) | ((unsigned)f2h(v0.y * 0.0625f) << 16);
                pk.y = f2h(v0.z * 0.0625f) | ((unsigned)f2h(v0.w * 0.0625f) << 16);
                pk.z = f2h(v1.x * 0.0625f) | ((unsigned)f2h(v1.y * 0.0625f) << 16);
                pk.w = f2h(v1.z * 0.0625f) | ((unsigned)f2h(v1.w * 0.0625f) << 16);
            }
        }
        *(uint4*)(smem + ((b * 256 + c16 * 16) ^ ((b & 7) << 4))) = pk;
    }
    __syncthreads();
    // MFMA: wave q -> ntiles 2q, 2q+1
    const uint4* bt = (const uint4*)wfr + (size_t)mat * 2048;
    f32x4 ac0 = {0.f, 0.f, 0.f, 0.f};
    f32x4 ac1 = {0.f, 0.f, 0.f, 0.f};
    int brow = lane & 15;
#pragma unroll
    for (int s = 0; s < 4; ++s) {
        half8 af = *(const half8*)(smem + ((brow * 256 + s * 64 + tg * 16) ^ ((brow & 7) << 4)));
        half8 bf0 = __builtin_bit_cast(half8, bt[(s * 8 + 2 * q) * 64 + lane]);
        half8 bf1 = __builtin_bit_cast(half8, bt[(s * 8 + 2 * q + 1) * 64 + lane]);
        ac0 = __builtin_amdgcn_mfma_f32_16x16x32_f16(af, bf0, ac0, 0, 0, 0);
        ac1 = __builtin_amdgcn_mfma_f32_16x16x32_f16(af, bf1, ac1, 0, 0, 0);
    }
    const float sc = 16.0f * 2.0f / 65536.0f;
#pragma unroll
    for (int n = 0; n < 2; ++n) {
        f32x4 ac = n ? ac1 : ac0;
        int col = (2 * q + n) * 16 + (lane & 15);
        int o = col >> 1, pp = col & 1;
#pragma unroll
        for (int r = 0; r < 4; ++r) {
            int bb = (lane >> 4) * 4 + r;
            if (bb < bc)
                Z[(((size_t)bb * 12 + ky) * 64 + o) * 48 + mm * 2 + pp] = ac[r] * sc;
        }
    }
}

// ------- H-DFT via MFMA: Xf[b][m][ky][i] from Xw[b][ky][hh][i][2] -------
__global__ __launch_bounds__(256) void k_dfth(const float* __restrict__ Xw,
                                              float* __restrict__ Xf2,
                                              const unsigned short* __restrict__ tfr) {
    __shared__ __align__(16) char smem[65536];
    int b = blockIdx.x / 12, ky = blockIdx.x % 12;
    int t = threadIdx.x;
    int lane = t & 63, q = t >> 6;
    const float* P = Xw + ((size_t)b * 12 + ky) * 32768;
    int c = lane;
#pragma unroll 4
    for (int k = 0; k < 32; ++k) {
        int hh0 = k * 8 + q * 2;
        float2 a  = *(const float2*)(P + hh0 * 128 + 2 * c);
        float2 bv = *(const float2*)(P + (hh0 + 1) * 128 + 2 * c);
        unsigned int u0 = f2h(a.x * 0.0625f) | ((unsigned int)f2h(bv.x * 0.0625f) << 16);
        unsigned int u1 = f2h(a.y * 0.0625f) | ((unsigned int)f2h(bv.y * 0.0625f) << 16);
        int ch0 = 2 * c, ch1 = 2 * c + 1;
        *(unsigned int*)(smem + ch0 * 512 + ((2 * hh0) ^ ((ch0 & 7) << 4))) = u0;
        *(unsigned int*)(smem + ch1 * 512 + ((2 * hh0) ^ ((ch1 & 7) << 4))) = u1;
    }
    __syncthreads();
    int ct0 = q * 2;
    int tg = (lane >> 4) & 3;
    f32x4 a00 = {0,0,0,0}, a01 = {0,0,0,0}, a10 = {0,0,0,0};
    f32x4 a11 = {0,0,0,0}, a20 = {0,0,0,0}, a21 = {0,0,0,0};
    const uint4* tf4 = (const uint4*)tfr;
#pragma unroll
    for (int s = 0; s < 8; ++s) {
        half8 af0 = __builtin_bit_cast(half8, tf4[(s * 3 + 0) * 64 + lane]);
        half8 af1 = __builtin_bit_cast(half8, tf4[(s * 3 + 1) * 64 + lane]);
        half8 af2 = __builtin_bit_cast(half8, tf4[(s * 3 + 2) * 64 + lane]);
        int chan0 = ct0 * 16 + (lane & 15);
        int chan1 = chan0 + 16;
        int off = s * 64 + tg * 16;
        half8 b0 = *(const half8*)(smem + chan0 * 512 + (off ^ ((chan0 & 7) << 4)));
        half8 b1 = *(const half8*)(smem + chan1 * 512 + (off ^ ((chan1 & 7) << 4)));
        a00 = __builtin_amdgcn_mfma_f32_16x16x32_f16(af0, b0, a00, 0, 0, 0);
        a01 = __builtin_amdgcn_mfma_f32_16x16x32_f16(af0, b1, a01, 0, 0, 0);
        a10 = __builtin_amdgcn_mfma_f32_16x16x32_f16(af1, b0, a10, 0, 0, 0);
        a11 = __builtin_amdgcn_mfma_f32_16x16x32_f16(af1, b1, a11, 0, 0, 0);
        a20 = __builtin_amdgcn_mfma_f32_16x16x32_f16(af2, b0, a20, 0, 0, 0);
        a21 = __builtin_amdgcn_mfma_f32_16x16x32_f16(af2, b1, a21, 0, 0, 0);
    }
    __syncthreads();
    float* Cs = (float*)smem;
    {
        int rl = (lane >> 4) * 4;
        int chan0 = ct0 * 16 + (lane & 15);
#pragma unroll
        for (int r = 0; r < 4; ++r) {
            Cs[(0  + rl + r) * 128 + chan0]      = a00[r];
            Cs[(0  + rl + r) * 128 + chan0 + 16] = a01[r];
            Cs[(16 + rl + r) * 128 + chan0]      = a10[r];
            Cs[(16 + rl + r) * 128 + chan0 + 16] = a11[r];
            Cs[(32 + rl + r) * 128 + chan0]      = a20[r];
            Cs[(32 + rl + r) * 128 + chan0 + 16] = a21[r];
        }
    }
    __syncthreads();
#pragma unroll
    for (int k = 0; k < 6; ++k) {
        int p = t + 256 * k;
        int m = p >> 6, i = p & 63;
        float r1 = Cs[m * 128 + 2 * i];
        float i1 = Cs[m * 128 + 2 * i + 1];
        float r2 = Cs[(24 + m) * 128 + 2 * i];
        float i2 = Cs[(24 + m) * 128 + 2 * i + 1];
        ((float2*)Xf2)[((size_t)b * 288 + m * 12 + ky) * 64 + i] =
            make_float2((r1 + i2) * 16.0f, (i1 - r2) * 16.0f);
    }
}

// ------- fused A: all-MFMA layer kernel (fp16-packed accumulators) -------
__global__ __launch_bounds__(256, 4) void k_fusedA(const float* xh,
        const float* __restrict__ Zb, const float* __restrict__ pwb,
        const float* __restrict__ w0, const float* __restrict__ b0v,
        float* hn, float* __restrict__ XwOut,
        const float* __restrict__ tcs,
        const unsigned short* __restrict__ bfr,
        const unsigned short* __restrict__ efr,
        const unsigned short* __restrict__ pwfr,
        int l, int first) {
    __shared__ __align__(16) char smem[37120];
    float* Ysh = (float*)smem;
    char*  Yfr = smem + 32768;
    float* csm = (float*)(smem + 36864);
    int b  = blockIdx.x >> 8;
    int hh = blockIdx.x & 255;
    int w  = threadIdx.x;
    int lane = w & 63, q = w >> 6;
    int tg = (lane >> 4) & 3;
    const float2* tc2 = (const float2*)tcs;
    if (w < NM) {
        int kx = (w < Mk) ? w : (232 + w);
        float2 cs = tc2[(kx * hh) & 255];
        csm[2 * w] = cs.x; csm[2 * w + 1] = cs.y;
    }
    __syncthreads();
    const float* Zbb = Zb + (size_t)b * 36864;
    const float4* cs4 = (const float4*)csm;
#pragma unroll
    for (int r3 = 0; r3 < 3; ++r3) {
        int p = w + 256 * r3;
        int o = p / Mk, ky = p % Mk;
        const float4* zv = (const float4*)(Zbb + ((size_t)ky * 64 + o) * 48);
        float yr = 0.f, yi = 0.f;
#pragma unroll
        for (int mm = 0; mm < 12; ++mm) {
            float4 z  = zv[mm];
            float4 cc = cs4[mm];
            yr += z.x * cc.x - z.y * cc.y + z.z * cc.z - z.w * cc.w;
            yi += z.x * cc.y + z.y * cc.x + z.z * cc.w + z.w * cc.z;
        }
        Ysh[p * 2] = yr; Ysh[p * 2 + 1] = yi;
    }
    __syncthreads();
    {
        int o = q * 16 + (lane & 15);
        unsigned pv[4];
#pragma unroll
        for (int jp = 0; jp < 4; ++jp) {
            unsigned short h2[2];
#pragma unroll
            for (int hzz = 0; hzz < 2; ++hzz) {
                int u = tg * 8 + jp * 2 + hzz;
                float v;
                if (u == 0) v = 0.5f * Ysh[o * 24];
                else if (u < 12) v = Ysh[o * 24 + 2 * u];
                else if (u < 24) v = Ysh[o * 24 + 2 * (u - 12) + 1];
                else v = 0.f;
                h2[hzz] = f2h(v);
            }
            pv[jp] = h2[0] | ((unsigned)h2[1] << 16);
        }
        uint4 pk = {pv[0], pv[1], pv[2], pv[3]};
        *(uint4*)(Yfr + (q * 64 + lane) * 16) = pk;
    }
    __syncthreads();
    {
        int swz = (w & 7) << 4;
        if (first) {
            float xv = xh[(size_t)b * HW + hh * 256 + w];
#pragma unroll
            for (int ic = 0; ic < 4; ++ic) {
                unsigned pv[8];
#pragma unroll
                for (int j2 = 0; j2 < 16; j2 += 2) {
                    float a0 = w0[ic * 16 + j2] * xv + b0v[ic * 16 + j2];
                    float a1 = w0[ic * 16 + j2 + 1] * xv + b0v[ic * 16 + j2 + 1];
                    pv[j2 >> 1] = f2h(a0) | ((unsigned)f2h(a1) << 16);
                }
                uint4 lo = {pv[0], pv[1], pv[2], pv[3]};
                uint4 hi = {pv[4], pv[5], pv[6], pv[7]};
                *(uint4*)(smem + ((w * 128 + ic * 32) ^ swz)) = lo;
                *(uint4*)(smem + ((w * 128 + ic * 32 + 16) ^ swz)) = hi;
            }
        } else {
            const float* hb = xh + (size_t)b * Cn * HW + hh * 256 + w;
#pragma unroll
            for (int ic = 0; ic < 4; ++ic) {
                unsigned pv[8];
#pragma unroll
                for (int j2 = 0; j2 < 16; j2 += 2) {
                    float a0 = hb[(size_t)(ic * 16 + j2) * HW];
                    float a1 = hb[(size_t)(ic * 16 + j2 + 1) * HW];
                    pv[j2 >> 1] = f2h(a0) | ((unsigned)f2h(a1) << 16);
                }
                uint4 lo = {pv[0], pv[1], pv[2], pv[3]};
                uint4 hi = {pv[4], pv[5], pv[6], pv[7]};
                *(uint4*)(smem + ((w * 128 + ic * 32) ^ swz)) = lo;
                *(uint4*)(smem + ((w * 128 + ic * 32 + 16) ^ swz)) = hi;
            }
        }
    }
    __syncthreads();
    // MFMA: C[pix][o] = E@Y + A@pw; +bias, gelu -> packed fp16 gp
    uint2 gp[4][4];
    {
        const uint4* efr4 = (const uint4*)efr;
        const uint4* pw4  = (const uint4*)pwfr;
        float biasn[4];
        half8 ybf[4]; uint4 cwa[4], cwb[4];
#pragma unroll
        for (int nt = 0; nt < 4; ++nt) {
            biasn[nt] = pwb[l * 64 + nt * 16 + (lane & 15)];
            ybf[nt] = *(const half8*)(Yfr + (nt * 64 + lane) * 16);
            cwa[nt] = pw4[((l * 2 + 0) * 4 + nt) * 64 + lane];
            cwb[nt] = pw4[((l * 2 + 1) * 4 + nt) * 64 + lane];
        }
#pragma unroll
        for (int mt = 0; mt < 4; ++mt) {
            int mtA = q * 4 + mt;
            half8 ea = __builtin_bit_cast(half8, efr4[mtA * 64 + lane]);
            int row = mtA * 16 + (lane & 15);
            int rsw = (row & 7) << 4;
            half8 a0 = *(const half8*)(smem + ((row * 128 + tg * 16) ^ rsw));
            half8 a1 = *(const half8*)(smem + ((row * 128 + 64 + tg * 16) ^ rsw));
#pragma unroll
            for (int nt = 0; nt < 4; ++nt) {
                f32x4 acc = {0.f, 0.f, 0.f, 0.f};
                acc = __builtin_amdgcn_mfma_f32_16x16x32_f16(ea, ybf[nt], acc, 0, 0, 0);
                acc = __builtin_amdgcn_mfma_f32_16x16x32_f16(a0, __builtin_bit_cast(half8, cwa[nt]), acc, 0, 0, 0);
                acc = __builtin_amdgcn_mfma_f32_16x16x32_f16(a1, __builtin_bit_cast(half8, cwb[nt]), acc, 0, 0, 0);
                float g0 = gelu_exact(acc[0] + biasn[nt]);
                float g1 = gelu_exact(acc[1] + biasn[nt]);
                float g2 = gelu_exact(acc[2] + biasn[nt]);
                float g3 = gelu_exact(acc[3] + biasn[nt]);
                gp[mt][nt].x = f2h(g0) | ((unsigned)f2h(g1) << 16);
                gp[mt][nt].y = f2h(g2) | ((unsigned)f2h(g3) << 16);
            }
        }
    }
    // global h stores (fp32 unpacked from fp16 — downstream re-converts anyway)
    float* hnb = hn + (size_t)b * Cn * HW + hh * 256;
#pragma unroll
    for (int mt = 0; mt < 4; ++mt) {
        int pbase = (q * 4 + mt) * 16 + (lane >> 4) * 4;
#pragma unroll
        for (int nt = 0; nt < 4; ++nt) {
            int o = nt * 16 + (lane & 15);
            uint2 g2 = gp[mt][nt];
            float4 hv = {h2lo(g2.x), h2hi(g2.x), h2lo(g2.y), h2hi(g2.y)};
            *(float4*)(hnb + (size_t)o * HW + pbase) = hv;
        }
    }
    __syncthreads();
#pragma unroll
    for (int mt = 0; mt < 4; ++mt) {
        int pbase = (q * 4 + mt) * 16 + (lane >> 4) * 4;
#pragma unroll
        for (int nt = 0; nt < 4; ++nt) {
            int o = nt * 16 + (lane & 15);
            int sidx = (((pbase >> 3) ^ (o & 7)) << 3) | (pbase & 7);
            *(uint2*)(smem + o * 512 + sidx * 2) = gp[mt][nt];
        }
    }
    __syncthreads();
    {
        int arow = q * 16 + (lane & 15);
        const uint4* bt = (const uint4*)bfr;
        f32x4 ac0 = {0.f, 0.f, 0.f, 0.f};
        f32x4 ac1 = {0.f, 0.f, 0.f, 0.f};
#pragma unroll
        for (int s = 0; s < 8; ++s) {
            int abyte = (arow * 512 + s * 64 + tg * 16) ^ ((arow & 7) << 4);
            half8 af = __builtin_bit_cast(half8, *(const uint4*)(smem + abyte));
            half8 b0 = __builtin_bit_cast(half8, bt[(s * 2 + 0) * 64 + lane]);
            half8 b1 = __builtin_bit_cast(half8, bt[(s * 2 + 1) * 64 + lane]);
            ac0 = __builtin_amdgcn_mfma_f32_16x16x32_f16(af, b0, ac0, 0, 0, 0);
            ac1 = __builtin_amdgcn_mfma_f32_16x16x32_f16(af, b1, ac1, 0, 0, 0);
        }
        float* Xwb = XwOut + (size_t)b * 393216;
        int rbase = q * 16 + (lane >> 4) * 4;
#pragma unroll
        for (int n = 0; n < 2; ++n) {
            f32x4 ac = n ? ac1 : ac0;
            int col = n * 16 + (lane & 15);
            int ky = col >> 1, p = col & 1;
            if (ky < Mk) {
                float* dst = Xwb + (size_t)ky * 32768 + hh * 128 + rbase * 2 + p;
                dst[0] = ac[0]; dst[2] = ac[1]; dst[4] = ac[2]; dst[6] = ac[3];
            }
        }
    }
}

// ------- fused B (layer 3): all-MFMA, fp16-packed R -------
__global__ __launch_bounds__(256, 4) void k_fusedB(const float* __restrict__ h,
        const float* __restrict__ Zb, const float* __restrict__ pwb,
        const float* __restrict__ fc1b, const float* __restrict__ fc2w,
        const float* __restrict__ fc2b, float* __restrict__ outp,
        const float* __restrict__ tcs,
        const unsigned short* __restrict__ efr,
        const unsigned short* __restrict__ pwfr,
        const unsigned short* __restrict__ fc1fr) {
    __shared__ __align__(16) char smem[37120];
    float* Ysh = (float*)smem;
    char*  Yfr = smem + 32768;
    float* csm = (float*)(smem + 36864);
    int b  = blockIdx.x >> 8;
    int hh = blockIdx.x & 255;
    int w  = threadIdx.x;
    int lane = w & 63, q = w >> 6;
    int tg = (lane >> 4) & 3;
    const float2* tc2 = (const float2*)tcs;
    if (w < NM) {
        int kx = (w < Mk) ? w : (232 + w);
        float2 cs = tc2[(kx * hh) & 255];
        csm[2 * w] = cs.x; csm[2 * w + 1] = cs.y;
    }
    __syncthreads();
    const float* Zbb = Zb + (size_t)b * 36864;
    const float4* cs4 = (const float4*)csm;
#pragma unroll
    for (int r3 = 0; r3 < 3; ++r3) {
        int p = w + 256 * r3;
        int o = p / Mk, ky = p % Mk;
        const float4* zv = (const float4*)(Zbb + ((size_t)ky * 64 + o) * 48);
        float yr = 0.f, yi = 0.f;
#pragma unroll
        for (int mm = 0; mm < 12; ++mm) {
            float4 z  = zv[mm];
            float4 cc = cs4[mm];
            yr += z.x * cc.x - z.y * cc.y + z.z * cc.z - z.w * cc.w;
            yi += z.x * cc.y + z.y * cc.x + z.z * cc.w + z.w * cc.z;
        }
        Ysh[p * 2] = yr; Ysh[p * 2 + 1] = yi;
    }
    __syncthreads();
    {
        int o = q * 16 + (lane & 15);
        unsigned pv[4];
#pragma unroll
        for (int jp = 0; jp < 4; ++jp) {
            unsigned short h2[2];
#pragma unroll
            for (int hzz = 0; hzz < 2; ++hzz) {
                int u = tg * 8 + jp * 2 + hzz;
                float v;
                if (u == 0) v = 0.5f * Ysh[o * 24];
                else if (u < 12) v = Ysh[o * 24 + 2 * u];
                else if (u < 24) v = Ysh[o * 24 + 2 * (u - 12) + 1];
                else v = 0.f;
                h2[hzz] = f2h(v);
            }
            pv[jp] = h2[0] | ((unsigned)h2[1] << 16);
        }
        uint4 pk = {pv[0], pv[1], pv[2], pv[3]};
        *(uint4*)(Yfr + (q * 64 + lane) * 16) = pk;
    }
    __syncthreads();
    {
        int swz = (w & 7) << 4;
        const float* hb = h + (size_t)b * Cn * HW + hh * 256 + w;
#pragma unroll
        for (int ic = 0; ic < 4; ++ic) {
            unsigned pv[8];
#pragma unroll
            for (int j2 = 0; j2 < 16; j2 += 2) {
                float a0 = hb[(size_t)(ic * 16 + j2) * HW];
                float a1 = hb[(size_t)(ic * 16 + j2 + 1) * HW];
                pv[j2 >> 1] = f2h(a0) | ((unsigned)f2h(a1) << 16);
            }
            uint4 lo = {pv[0], pv[1], pv[2], pv[3]};
            uint4 hi = {pv[4], pv[5], pv[6], pv[7]};
            *(uint4*)(smem + ((w * 128 + ic * 32) ^ swz)) = lo;
            *(uint4*)(smem + ((w * 128 + ic * 32 + 16) ^ swz)) = hi;
        }
    }
    __syncthreads();
    // conv+spec MFMA, M=o; R packed fp16 immediately (saves 32 VGPR)
    uint2 R2[16];
    {
        const uint4* efr4 = (const uint4*)efr;
        const uint4* pw4 = (const uint4*)pwfr;
        half8 ay  = *(const half8*)(Yfr + (q * 64 + lane) * 16);
        half8 aw0 = __builtin_bit_cast(half8, pw4[((3 * 2 + 0) * 4 + q) * 64 + lane]);
        half8 aw1 = __builtin_bit_cast(half8, pw4[((3 * 2 + 1) * 4 + q) * 64 + lane]);
        int obase = q * 16 + (lane >> 4) * 4;
        float4 bias4 = *(const float4*)(pwb + 3 * 64 + obase);
#pragma unroll
        for (int nt = 0; nt < 16; ++nt) {
            half8 eb = __builtin_bit_cast(half8, efr4[nt * 64 + lane]);
            int pix = nt * 16 + (lane & 15);
            int psw = (pix & 7) << 4;
            half8 b0 = *(const half8*)(smem + ((pix * 128 + tg * 16) ^ psw));
            half8 b1 = *(const half8*)(smem + ((pix * 128 + 64 + tg * 16) ^ psw));
            f32x4 acc = {0.f, 0.f, 0.f, 0.f};
            acc = __builtin_amdgcn_mfma_f32_16x16x32_f16(ay, eb, acc, 0, 0, 0);
            acc = __builtin_amdgcn_mfma_f32_16x16x32_f16(aw0, b0, acc, 0, 0, 0);
            acc = __builtin_amdgcn_mfma_f32_16x16x32_f16(aw1, b1, acc, 0, 0, 0);
            R2[nt].x = f2h(acc[0] + bias4.x) | ((unsigned)f2h(acc[1] + bias4.y) << 16);
            R2[nt].y = f2h(acc[2] + bias4.z) | ((unsigned)f2h(acc[3] + bias4.w) << 16);
        }
    }
    __syncthreads();
    {
        int obase = q * 16 + (lane >> 4) * 4;
#pragma unroll
        for (int nt = 0; nt < 16; ++nt) {
            int pix = nt * 16 + (lane & 15);
            *(uint2*)(smem + ((pix * 128 + obase * 2) ^ ((pix & 7) << 4))) = R2[nt];
        }
    }
    __syncthreads();
    const uint4* f14 = (const uint4*)fc1fr;
    float w2v[8], fb1[8];
#pragma unroll
    for (int nt = 0; nt < 8; ++nt) {
        w2v[nt] = fc2w[nt * 16 + (lane & 15)];
        fb1[nt] = fc1b[nt * 16 + (lane & 15)];
    }
    float fb = fc2b[0];
    float* ob = outp + (size_t)b * HW + hh * 256;
#pragma unroll
    for (int mt = 0; mt < 4; ++mt) {
        int mtA = q * 4 + mt;
        int row = mtA * 16 + (lane & 15);
        int rsw = (row & 7) << 4;
        half8 a0 = *(const half8*)(smem + ((row * 128 + tg * 16) ^ rsw));
        half8 a1 = *(const half8*)(smem + ((row * 128 + 64 + tg * 16) ^ rsw));
        float s0 = 0.f, s1 = 0.f, s2 = 0.f, s3 = 0.f;
#pragma unroll
        for (int nt = 0; nt < 8; ++nt) {
            f32x4 acc = {0.f, 0.f, 0.f, 0.f};
            acc = __builtin_amdgcn_mfma_f32_16x16x32_f16(a0, __builtin_bit_cast(half8, f14[(0 * 8 + nt) * 64 + lane]), acc, 0, 0, 0);
            acc = __builtin_amdgcn_mfma_f32_16x16x32_f16(a1, __builtin_bit_cast(half8, f14[(1 * 8 + nt) * 64 + lane]), acc, 0, 0, 0);
            s0 += gelu_exact(acc[0] + fb1[nt]) * w2v[nt];
            s1 += gelu_exact(acc[1] + fb1[nt]) * w2v[nt];
            s2 += gelu_exact(acc[2] + fb1[nt]) * w2v[nt];
            s3 += gelu_exact(acc[3] + fb1[nt]) * w2v[nt];
        }
#pragma unroll
        for (int msk = 1; msk <= 8; msk <<= 1) {
            s0 += __shfl_xor(s0, msk);
            s1 += __shfl_xor(s1, msk);
            s2 += __shfl_xor(s2, msk);
            s3 += __shfl_xor(s3, msk);
        }
        int cc = lane & 15;
        if (cc < 4) {
            float v = (cc == 0) ? s0 : (cc == 1) ? s1 : (cc == 2) ? s2 : s3;
            ob[mtA * 16 + (lane >> 4) * 4 + cc] = v + fb;
        }
    }
}

extern "C" void kernel_launch(void* const* d_in, const int* in_sizes, int n_in,
                              void* d_out, int out_size, void* d_ws, size_t ws_size,
                              hipStream_t stream) {
    const float* x    = (const float*)d_in[0];
    const float* fc0w = (const float*)d_in[1];
    const float* fc0b = (const float*)d_in[2];
    const float* scw  = (const float*)d_in[3];
    const float* pww  = (const float*)d_in[4];
    const float* pwb  = (const float*)d_in[5];
    const float* fc1w = (const float*)d_in[6];
    const float* fc1b = (const float*)d_in[7];
    const float* fc2w = (const float*)d_in[8];
    const float* fc2b = (const float*)d_in[9];
    float* out = (float*)d_out;
    float* ws  = (float*)d_ws;

    // base floats: 43008 small tables + scwT 9,437,184 + wfr 9,437,184 = 18,917,376
    const size_t basef = 18917376;
    const size_t perbf = 4661248;
    int bc = 0;
    for (int cand = 16; cand >= 1; cand >>= 1)
        if ((basef + perbf * (size_t)cand) * 4 <= ws_size) { bc = cand; break; }
    if (bc == 0) return;

    float* tabc = ws;
    float* tabs = tabc + 256;
    float* twc  = tabs + 256;
    float* tws_ = twc + 3072;
    float* tcs  = tws_ + 3072;
    float* bfr  = tcs + 512;            // fp16[8192]
    float* tfr  = bfr + 4096;           // fp16[12288]
    float* efr  = tfr + 6144;           // fp16[8192]
    float* pwfr = efr + 4096;           // fp16[16384]
    float* fc1f = pwfr + 8192;          // fp16[8192]
    float* Xfx  = fc1f + 4096;          // 9216
    float* scwT = Xfx + 9216;           // 9,437,184
    float* wfr  = scwT + 9437184;       // fp16[18,874,368]
    float* hbuf = ws + basef;
    float* Xw   = hbuf + (size_t)bc * 4194304;
    float* Zb   = Xw + (size_t)bc * 393216;
    float* Xf2  = Zb + (size_t)bc * 36864;

    k_init_tables<<<1, 256, 0, stream>>>(tabc, tabs, twc, tws_, tcs,
                                         (unsigned short*)bfr,
                                         (unsigned short*)tfr);
    k_prep_frag<<<128, 256, 0, stream>>>(pww, fc1w,
                                         (unsigned short*)efr,
                                         (unsigned short*)pwfr,
                                         (unsigned short*)fc1f);
    k_prep_w<<<9216, 256, 0, stream>>>(scw, scwT);
    k_prep_wfrag<<<1152, 256, 0, stream>>>(scwT, (unsigned short*)wfr);
    k_dftw_x<<<64, 64, 0, stream>>>(x, hbuf, twc, tws_);
    k_xdfth<<<18, 256, 0, stream>>>(hbuf, Xfx, tabc, tabs);

    for (int b0 = 0; b0 < 16; b0 += bc) {
        k_mixZ2<<<288, 256, 0, stream>>>(Xfx, (const unsigned short*)wfr,
                                         fc0w, fc0b, Zb, 0, 1, b0, bc);
        k_fusedA<<<bc * 256, 256, 0, stream>>>(x + (size_t)b0 * HW, Zb, pwb,
                                               fc0w, fc0b, hbuf, Xw, tcs,
                                               (const unsigned short*)bfr,
                                               (const unsigned short*)efr,
                                               (const unsigned short*)pwfr, 0, 1);
        for (int l = 1; l <= 2; ++l) {
            k_dfth<<<bc * 12, 256, 0, stream>>>(Xw, Xf2, (const unsigned short*)tfr);
            k_mixZ2<<<288, 256, 0, stream>>>(Xf2, (const unsigned short*)wfr,
                                             fc0w, fc0b, Zb, l, 0, b0, bc);
            k_fusedA<<<bc * 256, 256, 0, stream>>>(hbuf, Zb, pwb,
                                                   fc0w, fc0b, hbuf, Xw, tcs,
                                                   (const unsigned short*)bfr,
                                                   (const unsigned short*)efr,
                                                   (const unsigned short*)pwfr, l, 0);
        }
        k_dfth<<<bc * 12, 256, 0, stream>>>(Xw, Xf2, (const unsigned short*)tfr);
        k_mixZ2<<<288, 256, 0, stream>>>(Xf2, (const unsigned short*)wfr,
                                         fc0w, fc0b, Zb, 3, 0, b0, bc);
        k_fusedB<<<bc * 256, 256, 0, stream>>>(hbuf, Zb, pwb, fc1b, fc2w, fc2b,
                                               out + (size_t)b0 * HW, tcs,
                                               (const unsigned short*)efr,
                                               (const unsigned short*)pwfr,
                                               (const unsigned short*)fc1f);
    }
}

// Round 9
// 1577.162 us; speedup vs baseline: 1.0174x; 1.0174x over previous
//
#include <hip/hip_runtime.h>
#include <hip/hip_bf16.h>
#include <math.h>

#define Hn 256
#define Wn 256
#define Cn 64
#define Mk 12
#define NM 24
#define FCH 128
#define HW 65536

using half8 = __attribute__((ext_vector_type(8))) _Float16;
using f32x4 = __attribute__((ext_vector_type(4))) float;

__device__ __forceinline__ float gelu_exact(float x) {
    return 0.5f * x * (1.0f + erff(x * 0.7071067811865476f));
}
__device__ __forceinline__ unsigned short f2h(float f) {
    _Float16 h = (_Float16)f;
    return __builtin_bit_cast(unsigned short, h);
}

// ---------------- trig tables ----------------
__global__ __launch_bounds__(256) void k_init_tables(float* tc, float* ts,
                                                     float* twc, float* tws,
                                                     float* tcs,
                                                     unsigned short* bfr,
                                                     unsigned short* tfr) {
    int i = threadIdx.x;  // 0..255
    const float step = 0.024543692606170259f;  // 2*pi/256
    float c = cosf(i * step), s = sinf(i * step);
    tc[i] = c; ts[i] = s;
    tcs[2 * i] = c; tcs[2 * i + 1] = s;
    for (int k = 0; k < Mk; ++k) {
        int idx = (i * k) & 255;
        twc[i * Mk + k] = cosf(idx * step);
        tws[i * Mk + k] = sinf(idx * step);
    }
    for (int e = i; e < 8192; e += 256) {
        int j  = e & 7;
        int l  = (e >> 3) & 63;
        int sn = e >> 9;            // s*2+n
        int col = (sn & 1) * 16 + (l & 15);
        int ky = col >> 1, p = col & 1;
        int k  = (sn >> 1) * 32 + ((l >> 4) & 3) * 8 + j;
        int idx = (ky * k) & 255;
        float v = p ? -sinf(idx * step) : cosf(idx * step);
        bfr[e] = f2h(v);
    }
    for (int e = i; e < 12288; e += 256) {
        int j  = e & 7;
        int l  = (e >> 3) & 63;
        int sm = e >> 9;            // s*3+mt
        int mt = sm % 3, s2 = sm / 3;
        int r  = mt * 16 + (l & 15);
        int hh = s2 * 32 + ((l >> 4) & 3) * 8 + j;
        int m  = (r < 24) ? r : (r - 24);
        int kx = (m < Mk) ? m : (232 + m);
        int idx = (kx * hh) & 255;
        float v = (r < 24) ? cosf(idx * step) : sinf(idx * step);
        tfr[e] = f2h(v);
    }
}

// ---- weight/twiddle fragment tables for fusedA/fusedB ----
__global__ __launch_bounds__(256) void k_prep_frag(const float* __restrict__ pww,
                                                   const float* __restrict__ fc1w,
                                                   unsigned short* __restrict__ efr,
                                                   unsigned short* __restrict__ pwfr,
                                                   unsigned short* __restrict__ fc1fr) {
    int e = blockIdx.x * 256 + threadIdx.x;   // < 32768
    const float step = 0.024543692606170259f;
    int j = e & 7, l = (e >> 3) & 63;
    int row = l & 15;
    int k = ((l >> 4) & 3) * 8 + j;
    if (e < 8192) {
        int mt = (e >> 9) & 15;
        int pix = mt * 16 + row;
        float v = 0.f;
        if (k < 12) v = cosf(((k * pix) & 255) * step);
        else if (k < 24) v = -sinf((((k - 12) * pix) & 255) * step);
        efr[e] = f2h(v);
    } else if (e < 24576) {
        int e2 = e - 8192;
        int nt = (e2 >> 9) & 3;
        int ks = (e2 >> 11) & 1;
        int l4 = e2 >> 12;
        int o = nt * 16 + row;
        int i = ks * 32 + k;
        pwfr[e2] = f2h(pww[(size_t)(l4 * 64 + o) * 64 + i]);
    } else {
        int e2 = e - 24576;
        int nt = (e2 >> 9) & 7;
        int ks = (e2 >> 12) & 1;
        int d = nt * 16 + row;
        int i = ks * 32 + k;
        fc1fr[e2] = f2h(fc1w[i * 128 + d]);
    }
}

// ------- expand scw directly -> wfr fragment tables -------
// per matrix mat = lj*144 + kxw*12 + ky: B[k=2i+p][col=2o+pp]
// (p,pp)=(0,0):wr (0,1):wi (1,0):-wi (1,1):wr ; layout [mat][s4][nt8][lane][j8]
__global__ __launch_bounds__(256) void k_prep_wfrag(const float* __restrict__ scw,
                                                    unsigned short* __restrict__ wfr) {
    __shared__ float Ws[8192];
    int mat = blockIdx.x;            // lj*144 + kxw*12 + ky
    int lj = mat / 144, kxw = (mat / 12) % 12, ky = mat % 12;
    int t = threadIdx.x;
    const float* base = scw + (((size_t)lj * 4096) * 144 + kxw * 12 + ky) * 2;
#pragma unroll
    for (int r = 0; r < 16; ++r) {
        int idx = r * 256 + t;       // i*64+o
        float2 v = *(const float2*)(base + (size_t)idx * 288);
        Ws[idx * 2] = v.x; Ws[idx * 2 + 1] = v.y;
    }
    __syncthreads();
    unsigned short* dst = wfr + (size_t)mat * 16384;
#pragma unroll
    for (int u = 0; u < 8; ++u) {
        int lin = u * 256 + t;                 // (s*8+nt)*64 + lane
        int lane = lin & 63, nt = (lin >> 6) & 7, s = lin >> 9;
        int col = nt * 16 + (lane & 15);
        int o = col >> 1, pp = col & 1;
        int tg = (lane >> 4) & 3;
        unsigned pk[4];
#pragma unroll
        for (int jp = 0; jp < 4; ++jp) {
            unsigned short hv[2];
#pragma unroll
            for (int hz = 0; hz < 2; ++hz) {
                int k = s * 32 + tg * 8 + jp * 2 + hz;
                int i = k >> 1, p = k & 1;
                float wr_ = Ws[(i * 64 + o) * 2];
                float wi_ = Ws[(i * 64 + o) * 2 + 1];
                float v = (p == 0) ? (pp == 0 ? wr_ : wi_)
                                   : (pp == 0 ? -wi_ : wr_);
                hv[hz] = f2h(v);
            }
            pk[jp] = hv[0] | ((unsigned)hv[1] << 16);
        }
        uint4 w4 = {pk[0], pk[1], pk[2], pk[3]};
        *(uint4*)(dst + lin * 8) = w4;
    }
}

// ------- DFT along W of x (dedicated Xxw buffer) -------
__global__ __launch_bounds__(64) void k_dftw_x(const float* __restrict__ x,
                                               float* __restrict__ Xxw,
                                               const float* __restrict__ twc,
                                               const float* __restrict__ tws) {
    int r = blockIdx.x * 64 + threadIdx.x;
    const float* hp = x + (size_t)r * Wn;
    float xr[Mk], xi[Mk];
#pragma unroll
    for (int k = 0; k < Mk; ++k) { xr[k] = 0.f; xi[k] = 0.f; }
    for (int w4 = 0; w4 < 64; ++w4) {
        float4 v = ((const float4*)hp)[w4];
        float vv[4] = {v.x, v.y, v.z, v.w};
#pragma unroll
        for (int j = 0; j < 4; ++j) {
            int wbase = (w4 * 4 + j) * Mk;
#pragma unroll
            for (int k = 0; k < Mk; ++k) {
                xr[k] += vv[j] * twc[wbase + k];
                xi[k] -= vv[j] * tws[wbase + k];
            }
        }
    }
    float* op = Xxw + (size_t)r * (2 * Mk);
#pragma unroll
    for (int k = 0; k < Mk; ++k) { op[2 * k] = xr[k]; op[2 * k + 1] = xi[k]; }
}

// ------- DFT along H of x-modes -> Xfx[b][m][ky] -------
__global__ __launch_bounds__(256) void k_xdfth(const float* __restrict__ Xxw,
                                               float* __restrict__ Xfx,
                                               const float* __restrict__ tc,
                                               const float* __restrict__ ts) {
    int t = blockIdx.x * 256 + threadIdx.x;
    if (t >= 16 * 288) return;
    int ky = t % Mk;
    int m  = (t / Mk) % NM;
    int b  = t / 288;
    int kx = (m < Mk) ? m : (232 + m);
    const float* base = Xxw + (size_t)b * Hn * 2 * Mk + 2 * ky;
    float ar = 0.f, ai = 0.f;
    for (int hh = 0; hh < Hn; ++hh) {
        float vr = base[hh * 2 * Mk];
        float vi = base[hh * 2 * Mk + 1];
        int idx = (kx * hh) & 255;
        float c = tc[idx], s = ts[idx];
        ar += vr * c + vi * s;
        ai += vi * c - vr * s;
    }
    Xfx[2 * t] = ar;
    Xfx[2 * t + 1] = ai;
}

// ------- mode mix via MFMA (all layers; l=0 folds the lift), grid 576 -------
__global__ __launch_bounds__(256) void k_mixZ2(const float* __restrict__ xin,
                                               const unsigned short* __restrict__ wfr,
                                               const float* __restrict__ w0,
                                               const float* __restrict__ b0v,
                                               float* __restrict__ Z,
                                               int l, int first, int b0, int bc) {
    __shared__ __align__(16) char smem[4096];
    int t = threadIdx.x;
    int lane = t & 63, q = t >> 6, tg = (lane >> 4) & 3;
    int blk2 = blockIdx.x;
    int hlf = blk2 & 1;
    int blk = blk2 >> 1;
    int jj = blk / 144, kxw = (blk / 12) % 12, ky = blk % 12;
    int mm = jj * 12 + kxw;
    int mk = mm * 12 + ky;
    int mat = (l * 2 + jj) * 144 + kxw * 12 + ky;
    // stage A[b][k] fp16 (scaled 1/16), XOR-swizzled rows of 256B
    {
        int b = t >> 4, c16 = t & 15;
        uint4 pk = {0u, 0u, 0u, 0u};
        if (b < bc) {
            if (first) {
                float xr = xin[((b0 + b) * 288 + mk) * 2] * 0.0625f;
                float xi = xin[((b0 + b) * 288 + mk) * 2 + 1] * 0.0625f;
                float4 wv = *(const float4*)(w0 + c16 * 4);
                float4 bv = {0.f, 0.f, 0.f, 0.f};
                if (mk == 0) {
                    float4 bb = *(const float4*)(b0v + c16 * 4);
                    bv.x = 4096.f * bb.x; bv.y = 4096.f * bb.y;
                    bv.z = 4096.f * bb.z; bv.w = 4096.f * bb.w;
                }
                pk.x = f2h(wv.x * xr + bv.x) | ((unsigned)f2h(wv.x * xi) << 16);
                pk.y = f2h(wv.y * xr + bv.y) | ((unsigned)f2h(wv.y * xi) << 16);
                pk.z = f2h(wv.z * xr + bv.z) | ((unsigned)f2h(wv.z * xi) << 16);
                pk.w = f2h(wv.w * xr + bv.w) | ((unsigned)f2h(wv.w * xi) << 16);
            } else {
                const float* src = xin + ((size_t)b * 288 + mk) * 128 + c16 * 8;
                float4 v0 = *(const float4*)(src);
                float4 v1 = *(const float4*)(src + 4);
                pk.x = f2h(v0.x * 0.0625f) | ((unsigned)f2h(v0.y * 0.0625f) << 16);
                pk.y = f2h(v0.z * 0.0625f) | ((unsigned)f2h(v0.w * 0.0625f) << 16);
                pk.z = f2h(v1.x * 0.0625f) | ((unsigned)f2h(v1.y * 0.0625f) << 16);
                pk.w = f2h(v1.z * 0.0625f) | ((unsigned)f2h(v1.w * 0.0625f) << 16);
            }
        }
        *(uint4*)(smem + ((b * 256 + c16 * 16) ^ ((b & 7) << 4))) = pk;
    }
    __syncthreads();
    // MFMA: wave q -> ntile hlf*4+q
    int nt = hlf * 4 + q;
    const uint4* bt = (const uint4*)wfr + (size_t)mat * 2048;
    f32x4 ac = {0.f, 0.f, 0.f, 0.f};
    int brow = lane & 15;
#pragma unroll
    for (int s = 0; s < 4; ++s) {
        half8 af = *(const half8*)(smem + ((brow * 256 + s * 64 + tg * 16) ^ ((brow & 7) << 4)));
        half8 bf = __builtin_bit_cast(half8, bt[(s * 8 + nt) * 64 + lane]);
        ac = __builtin_amdgcn_mfma_f32_16x16x32_f16(af, bf, ac, 0, 0, 0);
    }
    const float sc = 16.0f * 2.0f / 65536.0f;
    int col = nt * 16 + (lane & 15);
    int o = col >> 1, pp = col & 1;
#pragma unroll
    for (int r = 0; r < 4; ++r) {
        int bb = (lane >> 4) * 4 + r;
        if (bb < bc)
            Z[(((size_t)bb * 12 + ky) * 64 + o) * 48 + mm * 2 + pp] = ac[r] * sc;
    }
}

// ------- H-DFT via MFMA: Xf[b][m][ky][i] from Xw[b][ky][hh][i][2] -------
__global__ __launch_bounds__(256) void k_dfth(const float* __restrict__ Xw,
                                              float* __restrict__ Xf2,
                                              const unsigned short* __restrict__ tfr) {
    __shared__ __align__(16) char smem[65536];
    int b = blockIdx.x / 12, ky = blockIdx.x % 12;
    int t = threadIdx.x;
    int lane = t & 63, q = t >> 6;
    const float* P = Xw + ((size_t)b * 12 + ky) * 32768;
    int c = lane;
#pragma unroll 4
    for (int k = 0; k < 32; ++k) {
        int hh0 = k * 8 + q * 2;
        float2 a  = *(const float2*)(P + hh0 * 128 + 2 * c);
        float2 bv = *(const float2*)(P + (hh0 + 1) * 128 + 2 * c);
        unsigned int u0 = f2h(a.x * 0.0625f) | ((unsigned int)f2h(bv.x * 0.0625f) << 16);
        unsigned int u1 = f2h(a.y * 0.0625f) | ((unsigned int)f2h(bv.y * 0.0625f) << 16);
        int ch0 = 2 * c, ch1 = 2 * c + 1;
        *(unsigned int*)(smem + ch0 * 512 + ((2 * hh0) ^ ((ch0 & 7) << 4))) = u0;
        *(unsigned int*)(smem + ch1 * 512 + ((2 * hh0) ^ ((ch1 & 7) << 4))) = u1;
    }
    __syncthreads();
    int ct0 = q * 2;
    int tg = (lane >> 4) & 3;
    f32x4 a00 = {0,0,0,0}, a01 = {0,0,0,0}, a10 = {0,0,0,0};
    f32x4 a11 = {0,0,0,0}, a20 = {0,0,0,0}, a21 = {0,0,0,0};
    const uint4* tf4 = (const uint4*)tfr;
#pragma unroll
    for (int s = 0; s < 8; ++s) {
        half8 af0 = __builtin_bit_cast(half8, tf4[(s * 3 + 0) * 64 + lane]);
        half8 af1 = __builtin_bit_cast(half8, tf4[(s * 3 + 1) * 64 + lane]);
        half8 af2 = __builtin_bit_cast(half8, tf4[(s * 3 + 2) * 64 + lane]);
        int chan0 = ct0 * 16 + (lane & 15);
        int chan1 = chan0 + 16;
        int off = s * 64 + tg * 16;
        half8 b0 = *(const half8*)(smem + chan0 * 512 + (off ^ ((chan0 & 7) << 4)));
        half8 b1 = *(const half8*)(smem + chan1 * 512 + (off ^ ((chan1 & 7) << 4)));
        a00 = __builtin_amdgcn_mfma_f32_16x16x32_f16(af0, b0, a00, 0, 0, 0);
        a01 = __builtin_amdgcn_mfma_f32_16x16x32_f16(af0, b1, a01, 0, 0, 0);
        a10 = __builtin_amdgcn_mfma_f32_16x16x32_f16(af1, b0, a10, 0, 0, 0);
        a11 = __builtin_amdgcn_mfma_f32_16x16x32_f16(af1, b1, a11, 0, 0, 0);
        a20 = __builtin_amdgcn_mfma_f32_16x16x32_f16(af2, b0, a20, 0, 0, 0);
        a21 = __builtin_amdgcn_mfma_f32_16x16x32_f16(af2, b1, a21, 0, 0, 0);
    }
    __syncthreads();
    float* Cs = (float*)smem;
    {
        int rl = (lane >> 4) * 4;
        int chan0 = ct0 * 16 + (lane & 15);
#pragma unroll
        for (int r = 0; r < 4; ++r) {
            Cs[(0  + rl + r) * 128 + chan0]      = a00[r];
            Cs[(0  + rl + r) * 128 + chan0 + 16] = a01[r];
            Cs[(16 + rl + r) * 128 + chan0]      = a10[r];
            Cs[(16 + rl + r) * 128 + chan0 + 16] = a11[r];
            Cs[(32 + rl + r) * 128 + chan0]      = a20[r];
            Cs[(32 + rl + r) * 128 + chan0 + 16] = a21[r];
        }
    }
    __syncthreads();
#pragma unroll
    for (int k = 0; k < 6; ++k) {
        int p = t + 256 * k;
        int m = p >> 6, i = p & 63;
        float r1 = Cs[m * 128 + 2 * i];
        float i1 = Cs[m * 128 + 2 * i + 1];
        float r2 = Cs[(24 + m) * 128 + 2 * i];
        float i2 = Cs[(24 + m) * 128 + 2 * i + 1];
        ((float2*)Xf2)[((size_t)b * 288 + m * 12 + ky) * 64 + i] =
            make_float2((r1 + i2) * 16.0f, (i1 - r2) * 16.0f);
    }
}

// ------- fused A: all-MFMA layer kernel, h stored fp16 -------
__global__ __launch_bounds__(256, 4) void k_fusedA(const float* __restrict__ x0,
        const unsigned short* hin,
        const float* __restrict__ Zb, const float* __restrict__ pwb,
        const float* __restrict__ w0, const float* __restrict__ b0v,
        unsigned short* hout, float* __restrict__ XwOut,
        const float* __restrict__ tcs,
        const unsigned short* __restrict__ bfr,
        const unsigned short* __restrict__ efr,
        const unsigned short* __restrict__ pwfr,
        int l, int first) {
    __shared__ __align__(16) char smem[37120];
    float* Ysh = (float*)smem;
    char*  Yfr = smem + 32768;
    float* csm = (float*)(smem + 36864);
    int b  = blockIdx.x >> 8;
    int hh = blockIdx.x & 255;
    int w  = threadIdx.x;
    int lane = w & 63, q = w >> 6;
    int tg = (lane >> 4) & 3;
    const float2* tc2 = (const float2*)tcs;
    if (w < NM) {
        int kx = (w < Mk) ? w : (232 + w);
        float2 cs = tc2[(kx * hh) & 255];
        csm[2 * w] = cs.x; csm[2 * w + 1] = cs.y;
    }
    __syncthreads();
    const float* Zbb = Zb + (size_t)b * 36864;
    const float4* cs4 = (const float4*)csm;
#pragma unroll
    for (int r3 = 0; r3 < 3; ++r3) {
        int p = w + 256 * r3;
        int o = p / Mk, ky = p % Mk;
        const float4* zv = (const float4*)(Zbb + ((size_t)ky * 64 + o) * 48);
        float yr = 0.f, yi = 0.f;
#pragma unroll
        for (int mm = 0; mm < 12; ++mm) {
            float4 z  = zv[mm];
            float4 cc = cs4[mm];
            yr += z.x * cc.x - z.y * cc.y + z.z * cc.z - z.w * cc.w;
            yi += z.x * cc.y + z.y * cc.x + z.z * cc.w + z.w * cc.z;
        }
        Ysh[p * 2] = yr; Ysh[p * 2 + 1] = yi;
    }
    __syncthreads();
    {
        int o = q * 16 + (lane & 15);
        unsigned pv[4];
#pragma unroll
        for (int jp = 0; jp < 4; ++jp) {
            unsigned short h2[2];
#pragma unroll
            for (int hzz = 0; hzz < 2; ++hzz) {
                int u = tg * 8 + jp * 2 + hzz;
                float v;
                if (u == 0) v = 0.5f * Ysh[o * 24];
                else if (u < 12) v = Ysh[o * 24 + 2 * u];
                else if (u < 24) v = Ysh[o * 24 + 2 * (u - 12) + 1];
                else v = 0.f;
                h2[hzz] = f2h(v);
            }
            pv[jp] = h2[0] | ((unsigned)h2[1] << 16);
        }
        uint4 pk = {pv[0], pv[1], pv[2], pv[3]};
        *(uint4*)(Yfr + (q * 64 + lane) * 16) = pk;
    }
    __syncthreads();
    {
        int swz = (w & 7) << 4;
        if (first) {
            float xv = x0[(size_t)b * HW + hh * 256 + w];
#pragma unroll
            for (int ic = 0; ic < 4; ++ic) {
                unsigned pv[8];
#pragma unroll
                for (int j2 = 0; j2 < 16; j2 += 2) {
                    float a0 = w0[ic * 16 + j2] * xv + b0v[ic * 16 + j2];
                    float a1 = w0[ic * 16 + j2 + 1] * xv + b0v[ic * 16 + j2 + 1];
                    pv[j2 >> 1] = f2h(a0) | ((unsigned)f2h(a1) << 16);
                }
                uint4 lo = {pv[0], pv[1], pv[2], pv[3]};
                uint4 hi = {pv[4], pv[5], pv[6], pv[7]};
                *(uint4*)(smem + ((w * 128 + ic * 32) ^ swz)) = lo;
                *(uint4*)(smem + ((w * 128 + ic * 32 + 16) ^ swz)) = hi;
            }
        } else {
            const unsigned short* hb = hin + (size_t)b * Cn * HW + hh * 256 + w;
#pragma unroll
            for (int ic = 0; ic < 4; ++ic) {
                unsigned pv[8];
#pragma unroll
                for (int j2 = 0; j2 < 16; j2 += 2) {
                    unsigned a0 = hb[(size_t)(ic * 16 + j2) * HW];
                    unsigned a1 = hb[(size_t)(ic * 16 + j2 + 1) * HW];
                    pv[j2 >> 1] = a0 | (a1 << 16);
                }
                uint4 lo = {pv[0], pv[1], pv[2], pv[3]};
                uint4 hi = {pv[4], pv[5], pv[6], pv[7]};
                *(uint4*)(smem + ((w * 128 + ic * 32) ^ swz)) = lo;
                *(uint4*)(smem + ((w * 128 + ic * 32 + 16) ^ swz)) = hi;
            }
        }
    }
    __syncthreads();
    // MFMA: C[pix][o] = E@Y + A@pw; +bias, gelu -> packed fp16 gp
    uint2 gp[4][4];
    {
        const uint4* efr4 = (const uint4*)efr;
        const uint4* pw4  = (const uint4*)pwfr;
        float biasn[4];
        half8 ybf[4]; uint4 cwa[4], cwb[4];
#pragma unroll
        for (int nt = 0; nt < 4; ++nt) {
            biasn[nt] = pwb[l * 64 + nt * 16 + (lane & 15)];
            ybf[nt] = *(const half8*)(Yfr + (nt * 64 + lane) * 16);
            cwa[nt] = pw4[((l * 2 + 0) * 4 + nt) * 64 + lane];
            cwb[nt] = pw4[((l * 2 + 1) * 4 + nt) * 64 + lane];
        }
#pragma unroll
        for (int mt = 0; mt < 4; ++mt) {
            int mtA = q * 4 + mt;
            half8 ea = __builtin_bit_cast(half8, efr4[mtA * 64 + lane]);
            int row = mtA * 16 + (lane & 15);
            int rsw = (row & 7) << 4;
            half8 a0 = *(const half8*)(smem + ((row * 128 + tg * 16) ^ rsw));
            half8 a1 = *(const half8*)(smem + ((row * 128 + 64 + tg * 16) ^ rsw));
#pragma unroll
            for (int nt = 0; nt < 4; ++nt) {
                f32x4 acc = {0.f, 0.f, 0.f, 0.f};
                acc = __builtin_amdgcn_mfma_f32_16x16x32_f16(ea, ybf[nt], acc, 0, 0, 0);
                acc = __builtin_amdgcn_mfma_f32_16x16x32_f16(a0, __builtin_bit_cast(half8, cwa[nt]), acc, 0, 0, 0);
                acc = __builtin_amdgcn_mfma_f32_16x16x32_f16(a1, __builtin_bit_cast(half8, cwb[nt]), acc, 0, 0, 0);
                float g0 = gelu_exact(acc[0] + biasn[nt]);
                float g1 = gelu_exact(acc[1] + biasn[nt]);
                float g2 = gelu_exact(acc[2] + biasn[nt]);
                float g3 = gelu_exact(acc[3] + biasn[nt]);
                gp[mt][nt].x = f2h(g0) | ((unsigned)f2h(g1) << 16);
                gp[mt][nt].y = f2h(g2) | ((unsigned)f2h(g3) << 16);
            }
        }
    }
    // global h stores: fp16 packed, uint2 (4 pix) per tile
    unsigned short* hnb = hout + (size_t)b * Cn * HW + hh * 256;
#pragma unroll
    for (int mt = 0; mt < 4; ++mt) {
        int pbase = (q * 4 + mt) * 16 + (lane >> 4) * 4;
#pragma unroll
        for (int nt = 0; nt < 4; ++nt) {
            int o = nt * 16 + (lane & 15);
            *(uint2*)(hnb + (size_t)o * HW + pbase) = gp[mt][nt];
        }
    }
    __syncthreads();
#pragma unroll
    for (int mt = 0; mt < 4; ++mt) {
        int pbase = (q * 4 + mt) * 16 + (lane >> 4) * 4;
#pragma unroll
        for (int nt = 0; nt < 4; ++nt) {
            int o = nt * 16 + (lane & 15);
            int sidx = (((pbase >> 3) ^ (o & 7)) << 3) | (pbase & 7);
            *(uint2*)(smem + o * 512 + sidx * 2) = gp[mt][nt];
        }
    }
    __syncthreads();
    {
        int arow = q * 16 + (lane & 15);
        const uint4* bt = (const uint4*)bfr;
        f32x4 ac0 = {0.f, 0.f, 0.f, 0.f};
        f32x4 ac1 = {0.f, 0.f, 0.f, 0.f};
#pragma unroll
        for (int s = 0; s < 8; ++s) {
            int abyte = (arow * 512 + s * 64 + tg * 16) ^ ((arow & 7) << 4);
            half8 af = __builtin_bit_cast(half8, *(const uint4*)(smem + abyte));
            half8 b0 = __builtin_bit_cast(half8, bt[(s * 2 + 0) * 64 + lane]);
            half8 b1 = __builtin_bit_cast(half8, bt[(s * 2 + 1) * 64 + lane]);
            ac0 = __builtin_amdgcn_mfma_f32_16x16x32_f16(af, b0, ac0, 0, 0, 0);
            ac1 = __builtin_amdgcn_mfma_f32_16x16x32_f16(af, b1, ac1, 0, 0, 0);
        }
        float* Xwb = XwOut + (size_t)b * 393216;
        int rbase = q * 16 + (lane >> 4) * 4;
#pragma unroll
        for (int n = 0; n < 2; ++n) {
            f32x4 ac = n ? ac1 : ac0;
            int col = n * 16 + (lane & 15);
            int ky = col >> 1, p = col & 1;
            if (ky < Mk) {
                float* dst = Xwb + (size_t)ky * 32768 + hh * 128 + rbase * 2 + p;
                dst[0] = ac[0]; dst[2] = ac[1]; dst[4] = ac[2]; dst[6] = ac[3];
            }
        }
    }
}

// ------- fused B (layer 3): all-MFMA, h read fp16 -------
__global__ __launch_bounds__(256, 4) void k_fusedB(const unsigned short* __restrict__ hin,
        const float* __restrict__ Zb, const float* __restrict__ pwb,
        const float* __restrict__ fc1b, const float* __restrict__ fc2w,
        const float* __restrict__ fc2b, float* __restrict__ outp,
        const float* __restrict__ tcs,
        const unsigned short* __restrict__ efr,
        const unsigned short* __restrict__ pwfr,
        const unsigned short* __restrict__ fc1fr) {
    __shared__ __align__(16) char smem[37120];
    float* Ysh = (float*)smem;
    char*  Yfr = smem + 32768;
    float* csm = (float*)(smem + 36864);
    int b  = blockIdx.x >> 8;
    int hh = blockIdx.x & 255;
    int w  = threadIdx.x;
    int lane = w & 63, q = w >> 6;
    int tg = (lane >> 4) & 3;
    const float2* tc2 = (const float2*)tcs;
    if (w < NM) {
        int kx = (w < Mk) ? w : (232 + w);
        float2 cs = tc2[(kx * hh) & 255];
        csm[2 * w] = cs.x; csm[2 * w + 1] = cs.y;
    }
    __syncthreads();
    const float* Zbb = Zb + (size_t)b * 36864;
    const float4* cs4 = (const float4*)csm;
#pragma unroll
    for (int r3 = 0; r3 < 3; ++r3) {
        int p = w + 256 * r3;
        int o = p / Mk, ky = p % Mk;
        const float4* zv = (const float4*)(Zbb + ((size_t)ky * 64 + o) * 48);
        float yr = 0.f, yi = 0.f;
#pragma unroll
        for (int mm = 0; mm < 12; ++mm) {
            float4 z  = zv[mm];
            float4 cc = cs4[mm];
            yr += z.x * cc.x - z.y * cc.y + z.z * cc.z - z.w * cc.w;
            yi += z.x * cc.y + z.y * cc.x + z.z * cc.w + z.w * cc.z;
        }
        Ysh[p * 2] = yr; Ysh[p * 2 + 1] = yi;
    }
    __syncthreads();
    {
        int o = q * 16 + (lane & 15);
        unsigned pv[4];
#pragma unroll
        for (int jp = 0; jp < 4; ++jp) {
            unsigned short h2[2];
#pragma unroll
            for (int hzz = 0; hzz < 2; ++hzz) {
                int u = tg * 8 + jp * 2 + hzz;
                float v;
                if (u == 0) v = 0.5f * Ysh[o * 24];
                else if (u < 12) v = Ysh[o * 24 + 2 * u];
                else if (u < 24) v = Ysh[o * 24 + 2 * (u - 12) + 1];
                else v = 0.f;
                h2[hzz] = f2h(v);
            }
            pv[jp] = h2[0] | ((unsigned)h2[1] << 16);
        }
        uint4 pk = {pv[0], pv[1], pv[2], pv[3]};
        *(uint4*)(Yfr + (q * 64 + lane) * 16) = pk;
    }
    __syncthreads();
    {
        int swz = (w & 7) << 4;
        const unsigned short* hb = hin + (size_t)b * Cn * HW + hh * 256 + w;
#pragma unroll
        for (int ic = 0; ic < 4; ++ic) {
            unsigned pv[8];
#pragma unroll
            for (int j2 = 0; j2 < 16; j2 += 2) {
                unsigned a0 = hb[(size_t)(ic * 16 + j2) * HW];
                unsigned a1 = hb[(size_t)(ic * 16 + j2 + 1) * HW];
                pv[j2 >> 1] = a0 | (a1 << 16);
            }
            uint4 lo = {pv[0], pv[1], pv[2], pv[3]};
            uint4 hi = {pv[4], pv[5], pv[6], pv[7]};
            *(uint4*)(smem + ((w * 128 + ic * 32) ^ swz)) = lo;
            *(uint4*)(smem + ((w * 128 + ic * 32 + 16) ^ swz)) = hi;
        }
    }
    __syncthreads();
    // conv+spec MFMA, M=o; R packed fp16
    uint2 R2[16];
    {
        const uint4* efr4 = (const uint4*)efr;
        const uint4* pw4 = (const uint4*)pwfr;
        half8 ay  = *(const half8*)(Yfr + (q * 64 + lane) * 16);
        half8 aw0 = __builtin_bit_cast(half8, pw4[((3 * 2 + 0) * 4 + q) * 64 + lane]);
        half8 aw1 = __builtin_bit_cast(half8, pw4[((3 * 2 + 1) * 4 + q) * 64 + lane]);
        int obase = q * 16 + (lane >> 4) * 4;
        float4 bias4 = *(const float4*)(pwb + 3 * 64 + obase);
#pragma unroll
        for (int nt = 0; nt < 16; ++nt) {
            half8 eb = __builtin_bit_cast(half8, efr4[nt * 64 + lane]);
            int pix = nt * 16 + (lane & 15);
            int psw = (pix & 7) << 4;
            half8 b0 = *(const half8*)(smem + ((pix * 128 + tg * 16) ^ psw));
            half8 b1 = *(const half8*)(smem + ((pix * 128 + 64 + tg * 16) ^ psw));
            f32x4 acc = {0.f, 0.f, 0.f, 0.f};
            acc = __builtin_amdgcn_mfma_f32_16x16x32_f16(ay, eb, acc, 0, 0, 0);
            acc = __builtin_amdgcn_mfma_f32_16x16x32_f16(aw0, b0, acc, 0, 0, 0);
            acc = __builtin_amdgcn_mfma_f32_16x16x32_f16(aw1, b1, acc, 0, 0, 0);
            R2[nt].x = f2h(acc[0] + bias4.x) | ((unsigned)f2h(acc[1] + bias4.y) << 16);
            R2[nt].y = f2h(acc[2] + bias4.z) | ((unsigned)f2h(acc[3] + bias4.w) << 16);
        }
    }
    __syncthreads();
    {
        int obase = q * 16 + (lane >> 4) * 4;
#pragma unroll
        for (int nt = 0; nt < 16; ++nt) {
            int pix = nt * 16 + (lane & 15);
            *(uint2*)(smem + ((pix * 128 + obase * 2) ^ ((pix & 7) << 4))) = R2[nt];
        }
    }
    __syncthreads();
    const uint4* f14 = (const uint4*)fc1fr;
    float w2v[8], fb1[8];
#pragma unroll
    for (int nt = 0; nt < 8; ++nt) {
        w2v[nt] = fc2w[nt * 16 + (lane & 15)];
        fb1[nt] = fc1b[nt * 16 + (lane & 15)];
    }
    float fb = fc2b[0];
    float* ob = outp + (size_t)b * HW + hh * 256;
#pragma unroll
    for (int mt = 0; mt < 4; ++mt) {
        int mtA = q * 4 + mt;
        int row = mtA * 16 + (lane & 15);
        int rsw = (row & 7) << 4;
        half8 a0 = *(const half8*)(smem + ((row * 128 + tg * 16) ^ rsw));
        half8 a1 = *(const half8*)(smem + ((row * 128 + 64 + tg * 16) ^ rsw));
        float s0 = 0.f, s1 = 0.f, s2 = 0.f, s3 = 0.f;
#pragma unroll
        for (int nt = 0; nt < 8; ++nt) {
            f32x4 acc = {0.f, 0.f, 0.f, 0.f};
            acc = __builtin_amdgcn_mfma_f32_16x16x32_f16(a0, __builtin_bit_cast(half8, f14[(0 * 8 + nt) * 64 + lane]), acc, 0, 0, 0);
            acc = __builtin_amdgcn_mfma_f32_16x16x32_f16(a1, __builtin_bit_cast(half8, f14[(1 * 8 + nt) * 64 + lane]), acc, 0, 0, 0);
            s0 += gelu_exact(acc[0] + fb1[nt]) * w2v[nt];
            s1 += gelu_exact(acc[1] + fb1[nt]) * w2v[nt];
            s2 += gelu_exact(acc[2] + fb1[nt]) * w2v[nt];
            s3 += gelu_exact(acc[3] + fb1[nt]) * w2v[nt];
        }
#pragma unroll
        for (int msk = 1; msk <= 8; msk <<= 1) {
            s0 += __shfl_xor(s0, msk);
            s1 += __shfl_xor(s1, msk);
            s2 += __shfl_xor(s2, msk);
            s3 += __shfl_xor(s3, msk);
        }
        int cc = lane & 15;
        if (cc < 4) {
            float v = (cc == 0) ? s0 : (cc == 1) ? s1 : (cc == 2) ? s2 : s3;
            ob[mtA * 16 + (lane >> 4) * 4 + cc] = v + fb;
        }
    }
}

extern "C" void kernel_launch(void* const* d_in, const int* in_sizes, int n_in,
                              void* d_out, int out_size, void* d_ws, size_t ws_size,
                              hipStream_t stream) {
    const float* x    = (const float*)d_in[0];
    const float* fc0w = (const float*)d_in[1];
    const float* fc0b = (const float*)d_in[2];
    const float* scw  = (const float*)d_in[3];
    const float* pww  = (const float*)d_in[4];
    const float* pwb  = (const float*)d_in[5];
    const float* fc1w = (const float*)d_in[6];
    const float* fc1b = (const float*)d_in[7];
    const float* fc2w = (const float*)d_in[8];
    const float* fc2b = (const float*)d_in[9];
    float* out = (float*)d_out;
    float* ws  = (float*)d_ws;

    // base floats: 43008 small tables + wfr 9,437,184 + Xxw 98,304 = 9,578,496
    // per batch: h16 2,097,152 + Xw 393,216 + Z 36,864 + Xf 36,864 = 2,564,096
    const size_t basef = 9578496;
    const size_t perbf = 2564096;
    int bc = 0;
    for (int cand = 16; cand >= 1; cand >>= 1)
        if ((basef + perbf * (size_t)cand) * 4 <= ws_size) { bc = cand; break; }
    if (bc == 0) return;

    float* tabc = ws;
    float* tabs = tabc + 256;
    float* twc  = tabs + 256;
    float* tws_ = twc + 3072;
    float* tcs  = tws_ + 3072;
    float* bfr  = tcs + 512;            // fp16[8192]
    float* tfr  = bfr + 4096;           // fp16[12288]
    float* efr  = tfr + 6144;           // fp16[8192]
    float* pwfr = efr + 4096;           // fp16[16384]
    float* fc1f = pwfr + 8192;          // fp16[8192]
    float* Xfx  = fc1f + 4096;          // 9216
    float* wfr  = Xfx + 9216;           // fp16[18,874,368]
    float* Xxw  = wfr + 9437184;        // 98,304 fp32 (prologue only)
    float* hbuf = ws + basef;           // bc*2,097,152 floats: h16
    unsigned short* h16 = (unsigned short*)hbuf;
    float* Xw   = hbuf + (size_t)bc * 2097152;
    float* Zb   = Xw + (size_t)bc * 393216;
    float* Xf2  = Zb + (size_t)bc * 36864;

    k_init_tables<<<1, 256, 0, stream>>>(tabc, tabs, twc, tws_, tcs,
                                         (unsigned short*)bfr,
                                         (unsigned short*)tfr);
    k_prep_frag<<<128, 256, 0, stream>>>(pww, fc1w,
                                         (unsigned short*)efr,
                                         (unsigned short*)pwfr,
                                         (unsigned short*)fc1f);
    k_prep_wfrag<<<1152, 256, 0, stream>>>(scw, (unsigned short*)wfr);
    k_dftw_x<<<64, 64, 0, stream>>>(x, Xxw, twc, tws_);
    k_xdfth<<<18, 256, 0, stream>>>(Xxw, Xfx, tabc, tabs);

    for (int b0 = 0; b0 < 16; b0 += bc) {
        k_mixZ2<<<576, 256, 0, stream>>>(Xfx, (const unsigned short*)wfr,
                                         fc0w, fc0b, Zb, 0, 1, b0, bc);
        k_fusedA<<<bc * 256, 256, 0, stream>>>(x + (size_t)b0 * HW, h16, Zb, pwb,
                                               fc0w, fc0b, h16, Xw, tcs,
                                               (const unsigned short*)bfr,
                                               (const unsigned short*)efr,
                                               (const unsigned short*)pwfr, 0, 1);
        for (int l = 1; l <= 2; ++l) {
            k_dfth<<<bc * 12, 256, 0, stream>>>(Xw, Xf2, (const unsigned short*)tfr);
            k_mixZ2<<<576, 256, 0, stream>>>(Xf2, (const unsigned short*)wfr,
                                             fc0w, fc0b, Zb, l, 0, b0, bc);
            k_fusedA<<<bc * 256, 256, 0, stream>>>(x, h16, Zb, pwb,
                                                   fc0w, fc0b, h16, Xw, tcs,
                                                   (const unsigned short*)bfr,
                                                   (const unsigned short*)efr,
                                                   (const unsigned short*)pwfr, l, 0);
        }
        k_dfth<<<bc * 12, 256, 0, stream>>>(Xw, Xf2, (const unsigned short*)tfr);
        k_mixZ2<<<576, 256, 0, stream>>>(Xf2, (const unsigned short*)wfr,
                                         fc0w, fc0b, Zb, 3, 0, b0, bc);
        k_fusedB<<<bc * 256, 256, 0, stream>>>(h16, Zb, pwb, fc1b, fc2w, fc2b,
                                               out + (size_t)b0 * HW, tcs,
                                               (const unsigned short*)efr,
                                               (const unsigned short*)pwfr,
                                               (const unsigned short*)fc1f);
    }
}

// Round 10
// 1320.885 us; speedup vs baseline: 1.2148x; 1.1940x over previous
//
#include <hip/hip_runtime.h>
#include <hip/hip_bf16.h>
#include <math.h>

#define Hn 256
#define Wn 256
#define Cn 64
#define Mk 12
#define NM 24
#define FCH 128
#define HW 65536

using half8 = __attribute__((ext_vector_type(8))) _Float16;
using f32x4 = __attribute__((ext_vector_type(4))) float;

__device__ __forceinline__ float gelu_exact(float x) {
    return 0.5f * x * (1.0f + erff(x * 0.7071067811865476f));
}
__device__ __forceinline__ unsigned short f2h(float f) {
    _Float16 h = (_Float16)f;
    return __builtin_bit_cast(unsigned short, h);
}

// ---------------- trig + fragment twiddle tables ----------------
// bfr: fusedA W-DFT B-frag; tfr: k_dfth H-DFT A-frag (as before)
// yfrA: k_prepY A-frag fp16 [s2][mt16][lane][j8]:
//   hh=mt*16+(l&15); k=s*32+((l>>4)&3)*8+j; m=k>>1,sgn=k&1;
//   m<24: kx=(m<12?m:232+m); val = sgn ? sin(kx hh) : cos(kx hh); else 0
__global__ __launch_bounds__(256) void k_init_tables(float* tc, float* ts,
                                                     float* twc, float* tws,
                                                     float* tcs,
                                                     unsigned short* bfr,
                                                     unsigned short* tfr,
                                                     unsigned short* yfrA) {
    int i = threadIdx.x;  // 0..255
    const float step = 0.024543692606170259f;  // 2*pi/256
    float c = cosf(i * step), s = sinf(i * step);
    tc[i] = c; ts[i] = s;
    tcs[2 * i] = c; tcs[2 * i + 1] = s;
    for (int k = 0; k < Mk; ++k) {
        int idx = (i * k) & 255;
        twc[i * Mk + k] = cosf(idx * step);
        tws[i * Mk + k] = sinf(idx * step);
    }
    for (int e = i; e < 8192; e += 256) {
        int j  = e & 7;
        int l  = (e >> 3) & 63;
        int sn = e >> 9;
        int col = (sn & 1) * 16 + (l & 15);
        int ky = col >> 1, p = col & 1;
        int k  = (sn >> 1) * 32 + ((l >> 4) & 3) * 8 + j;
        int idx = (ky * k) & 255;
        float v = p ? -sinf(idx * step) : cosf(idx * step);
        bfr[e] = f2h(v);
    }
    for (int e = i; e < 12288; e += 256) {
        int j  = e & 7;
        int l  = (e >> 3) & 63;
        int sm = e >> 9;
        int mt = sm % 3, s2 = sm / 3;
        int r  = mt * 16 + (l & 15);
        int hh = s2 * 32 + ((l >> 4) & 3) * 8 + j;
        int m  = (r < 24) ? r : (r - 24);
        int kx = (m < Mk) ? m : (232 + m);
        int idx = (kx * hh) & 255;
        float v = (r < 24) ? cosf(idx * step) : sinf(idx * step);
        tfr[e] = f2h(v);
    }
    for (int e = i; e < 16384; e += 256) {
        int j  = e & 7;
        int l  = (e >> 3) & 63;
        int sm = e >> 9;            // s*16+mt
        int mt = sm & 15, s2 = sm >> 4;
        int hh = mt * 16 + (l & 15);
        int k  = s2 * 32 + ((l >> 4) & 3) * 8 + j;
        int m = k >> 1, sgn = k & 1;
        float v = 0.f;
        if (m < 24) {
            int kx = (m < Mk) ? m : (232 + m);
            int idx = (kx * hh) & 255;
            v = sgn ? sinf(idx * step) : cosf(idx * step);
        }
        yfrA[e] = f2h(v);
    }
}

// ---- weight/twiddle fragment tables for fusedA/fusedB ----
__global__ __launch_bounds__(256) void k_prep_frag(const float* __restrict__ pww,
                                                   const float* __restrict__ fc1w,
                                                   unsigned short* __restrict__ efr,
                                                   unsigned short* __restrict__ pwfr,
                                                   unsigned short* __restrict__ fc1fr) {
    int e = blockIdx.x * 256 + threadIdx.x;   // < 32768
    const float step = 0.024543692606170259f;
    int j = e & 7, l = (e >> 3) & 63;
    int row = l & 15;
    int k = ((l >> 4) & 3) * 8 + j;
    if (e < 8192) {
        int mt = (e >> 9) & 15;
        int pix = mt * 16 + row;
        float v = 0.f;
        if (k < 12) v = cosf(((k * pix) & 255) * step);
        else if (k < 24) v = -sinf((((k - 12) * pix) & 255) * step);
        efr[e] = f2h(v);
    } else if (e < 24576) {
        int e2 = e - 8192;
        int nt = (e2 >> 9) & 3;
        int ks = (e2 >> 11) & 1;
        int l4 = e2 >> 12;
        int o = nt * 16 + row;
        int i = ks * 32 + k;
        pwfr[e2] = f2h(pww[(size_t)(l4 * 64 + o) * 64 + i]);
    } else {
        int e2 = e - 24576;
        int nt = (e2 >> 9) & 7;
        int ks = (e2 >> 12) & 1;
        int d = nt * 16 + row;
        int i = ks * 32 + k;
        fc1fr[e2] = f2h(fc1w[i * 128 + d]);
    }
}

// ------- expand scw directly -> wfr fragment tables -------
__global__ __launch_bounds__(256) void k_prep_wfrag(const float* __restrict__ scw,
                                                    unsigned short* __restrict__ wfr) {
    __shared__ float Ws[8192];
    int mat = blockIdx.x;            // lj*144 + kxw*12 + ky
    int lj = mat / 144, kxw = (mat / 12) % 12, ky = mat % 12;
    int t = threadIdx.x;
    const float* base = scw + (((size_t)lj * 4096) * 144 + kxw * 12 + ky) * 2;
#pragma unroll
    for (int r = 0; r < 16; ++r) {
        int idx = r * 256 + t;       // i*64+o
        float2 v = *(const float2*)(base + (size_t)idx * 288);
        Ws[idx * 2] = v.x; Ws[idx * 2 + 1] = v.y;
    }
    __syncthreads();
    unsigned short* dst = wfr + (size_t)mat * 16384;
#pragma unroll
    for (int u = 0; u < 8; ++u) {
        int lin = u * 256 + t;
        int lane = lin & 63, nt = (lin >> 6) & 7, s = lin >> 9;
        int col = nt * 16 + (lane & 15);
        int o = col >> 1, pp = col & 1;
        int tg = (lane >> 4) & 3;
        unsigned pk[4];
#pragma unroll
        for (int jp = 0; jp < 4; ++jp) {
            unsigned short hv[2];
#pragma unroll
            for (int hz = 0; hz < 2; ++hz) {
                int k = s * 32 + tg * 8 + jp * 2 + hz;
                int i = k >> 1, p = k & 1;
                float wr_ = Ws[(i * 64 + o) * 2];
                float wi_ = Ws[(i * 64 + o) * 2 + 1];
                float v = (p == 0) ? (pp == 0 ? wr_ : wi_)
                                   : (pp == 0 ? -wi_ : wr_);
                hv[hz] = f2h(v);
            }
            pk[jp] = hv[0] | ((unsigned)hv[1] << 16);
        }
        uint4 w4 = {pk[0], pk[1], pk[2], pk[3]};
        *(uint4*)(dst + lin * 8) = w4;
    }
}

// ------- DFT along W of x -------
__global__ __launch_bounds__(64) void k_dftw_x(const float* __restrict__ x,
                                               float* __restrict__ Xxw,
                                               const float* __restrict__ twc,
                                               const float* __restrict__ tws) {
    int r = blockIdx.x * 64 + threadIdx.x;
    const float* hp = x + (size_t)r * Wn;
    float xr[Mk], xi[Mk];
#pragma unroll
    for (int k = 0; k < Mk; ++k) { xr[k] = 0.f; xi[k] = 0.f; }
    for (int w4 = 0; w4 < 64; ++w4) {
        float4 v = ((const float4*)hp)[w4];
        float vv[4] = {v.x, v.y, v.z, v.w};
#pragma unroll
        for (int j = 0; j < 4; ++j) {
            int wbase = (w4 * 4 + j) * Mk;
#pragma unroll
            for (int k = 0; k < Mk; ++k) {
                xr[k] += vv[j] * twc[wbase + k];
                xi[k] -= vv[j] * tws[wbase + k];
            }
        }
    }
    float* op = Xxw + (size_t)r * (2 * Mk);
#pragma unroll
    for (int k = 0; k < Mk; ++k) { op[2 * k] = xr[k]; op[2 * k + 1] = xi[k]; }
}

// ------- DFT along H of x-modes -> Xfx[b][m][ky] -------
__global__ __launch_bounds__(256) void k_xdfth(const float* __restrict__ Xxw,
                                               float* __restrict__ Xfx,
                                               const float* __restrict__ tc,
                                               const float* __restrict__ ts) {
    int t = blockIdx.x * 256 + threadIdx.x;
    if (t >= 16 * 288) return;
    int ky = t % Mk;
    int m  = (t / Mk) % NM;
    int b  = t / 288;
    int kx = (m < Mk) ? m : (232 + m);
    const float* base = Xxw + (size_t)b * Hn * 2 * Mk + 2 * ky;
    float ar = 0.f, ai = 0.f;
    for (int hh = 0; hh < Hn; ++hh) {
        float vr = base[hh * 2 * Mk];
        float vi = base[hh * 2 * Mk + 1];
        int idx = (kx * hh) & 255;
        float c = tc[idx], s = ts[idx];
        ar += vr * c + vi * s;
        ai += vi * c - vr * s;
    }
    Xfx[2 * t] = ar;
    Xfx[2 * t + 1] = ai;
}

// ------- mode mix via MFMA (all layers; l=0 folds the lift), grid 576 -------
__global__ __launch_bounds__(256) void k_mixZ2(const float* __restrict__ xin,
                                               const unsigned short* __restrict__ wfr,
                                               const float* __restrict__ w0,
                                               const float* __restrict__ b0v,
                                               float* __restrict__ Z,
                                               int l, int first, int b0, int bc) {
    __shared__ __align__(16) char smem[4096];
    int t = threadIdx.x;
    int lane = t & 63, q = t >> 6, tg = (lane >> 4) & 3;
    int blk2 = blockIdx.x;
    int hlf = blk2 & 1;
    int blk = blk2 >> 1;
    int jj = blk / 144, kxw = (blk / 12) % 12, ky = blk % 12;
    int mm = jj * 12 + kxw;
    int mk = mm * 12 + ky;
    int mat = (l * 2 + jj) * 144 + kxw * 12 + ky;
    {
        int b = t >> 4, c16 = t & 15;
        uint4 pk = {0u, 0u, 0u, 0u};
        if (b < bc) {
            if (first) {
                float xr = xin[((b0 + b) * 288 + mk) * 2] * 0.0625f;
                float xi = xin[((b0 + b) * 288 + mk) * 2 + 1] * 0.0625f;
                float4 wv = *(const float4*)(w0 + c16 * 4);
                float4 bv = {0.f, 0.f, 0.f, 0.f};
                if (mk == 0) {
                    float4 bb = *(const float4*)(b0v + c16 * 4);
                    bv.x = 4096.f * bb.x; bv.y = 4096.f * bb.y;
                    bv.z = 4096.f * bb.z; bv.w = 4096.f * bb.w;
                }
                pk.x = f2h(wv.x * xr + bv.x) | ((unsigned)f2h(wv.x * xi) << 16);
                pk.y = f2h(wv.y * xr + bv.y) | ((unsigned)f2h(wv.y * xi) << 16);
                pk.z = f2h(wv.z * xr + bv.z) | ((unsigned)f2h(wv.z * xi) << 16);
                pk.w = f2h(wv.w * xr + bv.w) | ((unsigned)f2h(wv.w * xi) << 16);
            } else {
                const float* src = xin + ((size_t)b * 288 + mk) * 128 + c16 * 8;
                float4 v0 = *(const float4*)(src);
                float4 v1 = *(const float4*)(src + 4);
                pk.x = f2h(v0.x * 0.0625f) | ((unsigned)f2h(v0.y * 0.0625f) << 16);
                pk.y = f2h(v0.z * 0.0625f) | ((unsigned)f2h(v0.w * 0.0625f) << 16);
                pk.z = f2h(v1.x * 0.0625f) | ((unsigned)f2h(v1.y * 0.0625f) << 16);
                pk.w = f2h(v1.z * 0.0625f) | ((unsigned)f2h(v1.w * 0.0625f) << 16);
            }
        }
        *(uint4*)(smem + ((b * 256 + c16 * 16) ^ ((b & 7) << 4))) = pk;
    }
    __syncthreads();
    int nt = hlf * 4 + q;
    const uint4* bt = (const uint4*)wfr + (size_t)mat * 2048;
    f32x4 ac = {0.f, 0.f, 0.f, 0.f};
    int brow = lane & 15;
#pragma unroll
    for (int s = 0; s < 4; ++s) {
        half8 af = *(const half8*)(smem + ((brow * 256 + s * 64 + tg * 16) ^ ((brow & 7) << 4)));
        half8 bf = __builtin_bit_cast(half8, bt[(s * 8 + nt) * 64 + lane]);
        ac = __builtin_amdgcn_mfma_f32_16x16x32_f16(af, bf, ac, 0, 0, 0);
    }
    const float sc = 16.0f * 2.0f / 65536.0f;
    int col = nt * 16 + (lane & 15);
    int o = col >> 1, pp = col & 1;
#pragma unroll
    for (int r = 0; r < 4; ++r) {
        int bb = (lane >> 4) * 4 + r;
        if (bb < bc)
            Z[(((size_t)bb * 12 + ky) * 64 + o) * 48 + mm * 2 + pp] = ac[r] * sc;
    }
}

// ------- NEW: precompute Y = idft_h(Z) in consumer fragment layout -------
// Per (b,ky): C[256 hh][col=2o+sy] = T(256x48) @ Zexp(48x128); write fp16
// Ybuf[b][hh][o][u], u=ky+12*sy (u==0 halved); ky==0 blocks zero u in [24,32)
__global__ __launch_bounds__(256) void k_prepY(const float* __restrict__ Z,
                                               const unsigned short* __restrict__ yfrA,
                                               unsigned short* __restrict__ Ybuf) {
    __shared__ __align__(16) unsigned short bf[8192];  // [s2][nt8][lane][j8]
    int blkb = blockIdx.x / 12, ky = blockIdx.x % 12;
    int t = threadIdx.x;
    int lane = t & 63, q = t >> 6;
    const float* Zbb = Z + ((size_t)blkb * 12 + ky) * 3072;   // [o][48]
#pragma unroll
    for (int u4 = 0; u4 < 4; ++u4) {
        int lin = u4 * 256 + t;
        int lane_ = lin & 63, nt_ = (lin >> 6) & 7, s_ = lin >> 9;
        int tg_ = (lane_ >> 4) & 3;
        int col = nt_ * 16 + (lane_ & 15);
        int o = col >> 1, sy = col & 1;
        int kbase = s_ * 32 + tg_ * 8;
        uint4 pk = {0u, 0u, 0u, 0u};
        if (kbase < 48) {
            const float* zp = Zbb + o * 48 + kbase;
            float4 z0 = *(const float4*)zp;
            float4 z1 = *(const float4*)(zp + 4);
            float zv[8] = {z0.x, z0.y, z0.z, z0.w, z1.x, z1.y, z1.z, z1.w};
            unsigned pv[4];
#pragma unroll
            for (int jp = 0; jp < 4; ++jp) {
                float v0, v1;
                if (sy == 0) { v0 = zv[2 * jp];     v1 = -zv[2 * jp + 1]; }
                else         { v0 = zv[2 * jp + 1]; v1 = zv[2 * jp]; }
                pv[jp] = f2h(v0) | ((unsigned)f2h(v1) << 16);
            }
            pk.x = pv[0]; pk.y = pv[1]; pk.z = pv[2]; pk.w = pv[3];
        }
        *(uint4*)(bf + lin * 8) = pk;
    }
    __syncthreads();
    const uint4* A4 = (const uint4*)yfrA;
    const uint4* B4 = (const uint4*)bf;
    unsigned short* Yb = Ybuf + (size_t)blkb * 524288;
    float dcs = (ky == 0) ? 0.5f : 1.0f;
#pragma unroll
    for (int mtl = 0; mtl < 4; ++mtl) {
        int mt = q * 4 + mtl;
        half8 a0 = __builtin_bit_cast(half8, A4[(0 * 16 + mt) * 64 + lane]);
        half8 a1 = __builtin_bit_cast(half8, A4[(1 * 16 + mt) * 64 + lane]);
#pragma unroll
        for (int nt_ = 0; nt_ < 8; ++nt_) {
            f32x4 acc = {0.f, 0.f, 0.f, 0.f};
            acc = __builtin_amdgcn_mfma_f32_16x16x32_f16(a0,
                    __builtin_bit_cast(half8, B4[(0 * 8 + nt_) * 64 + lane]), acc, 0, 0, 0);
            acc = __builtin_amdgcn_mfma_f32_16x16x32_f16(a1,
                    __builtin_bit_cast(half8, B4[(1 * 8 + nt_) * 64 + lane]), acc, 0, 0, 0);
            int col = nt_ * 16 + (lane & 15);
            int o = col >> 1, sy = col & 1;
            int u = ky + 12 * sy;
            float sc2 = (sy == 0) ? dcs : 1.0f;
            int rbase = mt * 16 + (lane >> 4) * 4;
#pragma unroll
            for (int r = 0; r < 4; ++r)
                Yb[((size_t)(rbase + r) * 64 + o) * 32 + u] = f2h(acc[r] * sc2);
        }
    }
    if (ky == 0) {
        uint4 z4 = {0u, 0u, 0u, 0u};
        for (int e = t; e < 16384; e += 256)
            *(uint4*)(Yb + (size_t)e * 32 + 24) = z4;
    }
}

// ------- H-DFT via MFMA, fp16 planar Xw input [b][ky][p][hh][i] (x1/16) ----
__global__ __launch_bounds__(256) void k_dfth(const unsigned short* __restrict__ Xw,
                                              float* __restrict__ Xf2,
                                              const unsigned short* __restrict__ tfr) {
    __shared__ __align__(16) char smem[65536];
    int b = blockIdx.x / 12, ky = blockIdx.x % 12;
    int t = threadIdx.x;
    int lane = t & 63, q = t >> 6;
    const unsigned short* Pre = Xw + ((size_t)b * 24 + ky * 2) * 16384;
    const unsigned short* Pim = Pre + 16384;
    int c = lane;
#pragma unroll 4
    for (int k = 0; k < 32; ++k) {
        int hh0 = k * 8 + q * 2;
        unsigned r0 = Pre[hh0 * 64 + c], r1 = Pre[(hh0 + 1) * 64 + c];
        unsigned i0 = Pim[hh0 * 64 + c], i1 = Pim[(hh0 + 1) * 64 + c];
        unsigned u0 = r0 | (r1 << 16);
        unsigned u1 = i0 | (i1 << 16);
        int ch0 = 2 * c, ch1 = 2 * c + 1;
        *(unsigned int*)(smem + ch0 * 512 + ((2 * hh0) ^ ((ch0 & 7) << 4))) = u0;
        *(unsigned int*)(smem + ch1 * 512 + ((2 * hh0) ^ ((ch1 & 7) << 4))) = u1;
    }
    __syncthreads();
    int ct0 = q * 2;
    int tg = (lane >> 4) & 3;
    f32x4 a00 = {0,0,0,0}, a01 = {0,0,0,0}, a10 = {0,0,0,0};
    f32x4 a11 = {0,0,0,0}, a20 = {0,0,0,0}, a21 = {0,0,0,0};
    const uint4* tf4 = (const uint4*)tfr;
#pragma unroll
    for (int s = 0; s < 8; ++s) {
        half8 af0 = __builtin_bit_cast(half8, tf4[(s * 3 + 0) * 64 + lane]);
        half8 af1 = __builtin_bit_cast(half8, tf4[(s * 3 + 1) * 64 + lane]);
        half8 af2 = __builtin_bit_cast(half8, tf4[(s * 3 + 2) * 64 + lane]);
        int chan0 = ct0 * 16 + (lane & 15);
        int chan1 = chan0 + 16;
        int off = s * 64 + tg * 16;
        half8 b0 = *(const half8*)(smem + chan0 * 512 + (off ^ ((chan0 & 7) << 4)));
        half8 b1 = *(const half8*)(smem + chan1 * 512 + (off ^ ((chan1 & 7) << 4)));
        a00 = __builtin_amdgcn_mfma_f32_16x16x32_f16(af0, b0, a00, 0, 0, 0);
        a01 = __builtin_amdgcn_mfma_f32_16x16x32_f16(af0, b1, a01, 0, 0, 0);
        a10 = __builtin_amdgcn_mfma_f32_16x16x32_f16(af1, b0, a10, 0, 0, 0);
        a11 = __builtin_amdgcn_mfma_f32_16x16x32_f16(af1, b1, a11, 0, 0, 0);
        a20 = __builtin_amdgcn_mfma_f32_16x16x32_f16(af2, b0, a20, 0, 0, 0);
        a21 = __builtin_amdgcn_mfma_f32_16x16x32_f16(af2, b1, a21, 0, 0, 0);
    }
    __syncthreads();
    float* Cs = (float*)smem;
    {
        int rl = (lane >> 4) * 4;
        int chan0 = ct0 * 16 + (lane & 15);
#pragma unroll
        for (int r = 0; r < 4; ++r) {
            Cs[(0  + rl + r) * 128 + chan0]      = a00[r];
            Cs[(0  + rl + r) * 128 + chan0 + 16] = a01[r];
            Cs[(16 + rl + r) * 128 + chan0]      = a10[r];
            Cs[(16 + rl + r) * 128 + chan0 + 16] = a11[r];
            Cs[(32 + rl + r) * 128 + chan0]      = a20[r];
            Cs[(32 + rl + r) * 128 + chan0 + 16] = a21[r];
        }
    }
    __syncthreads();
#pragma unroll
    for (int k = 0; k < 6; ++k) {
        int p = t + 256 * k;
        int m = p >> 6, i = p & 63;
        float r1 = Cs[m * 128 + 2 * i];
        float i1 = Cs[m * 128 + 2 * i + 1];
        float r2 = Cs[(24 + m) * 128 + 2 * i];
        float i2 = Cs[(24 + m) * 128 + 2 * i + 1];
        ((float2*)Xf2)[((size_t)b * 288 + m * 12 + ky) * 64 + i] =
            make_float2((r1 + i2) * 16.0f, (i1 - r2) * 16.0f);
    }
}

// ------- fused A: Y from global frags; h fp16; Xw fp16 planar -------
__global__ __launch_bounds__(256, 4) void k_fusedA(const float* __restrict__ x0,
        const unsigned short* hin, const unsigned short* __restrict__ Ybuf,
        const float* __restrict__ pwb,
        const float* __restrict__ w0, const float* __restrict__ b0v,
        unsigned short* hout, unsigned short* __restrict__ XwOut,
        const unsigned short* __restrict__ bfr,
        const unsigned short* __restrict__ efr,
        const unsigned short* __restrict__ pwfr,
        int l, int first) {
    __shared__ __align__(16) char smem[32768];
    int b  = blockIdx.x >> 8;
    int hh = blockIdx.x & 255;
    int w  = threadIdx.x;
    int lane = w & 63, q = w >> 6;
    int tg = (lane >> 4) & 3;
    // A-stage: h_old (or lift of x) -> A_lds[pix=w][i] fp16, XOR-swizzled
    {
        int swz = (w & 7) << 4;
        if (first) {
            float xv = x0[(size_t)b * HW + hh * 256 + w];
#pragma unroll
            for (int ic = 0; ic < 4; ++ic) {
                unsigned pv[8];
#pragma unroll
                for (int j2 = 0; j2 < 16; j2 += 2) {
                    float a0 = w0[ic * 16 + j2] * xv + b0v[ic * 16 + j2];
                    float a1 = w0[ic * 16 + j2 + 1] * xv + b0v[ic * 16 + j2 + 1];
                    pv[j2 >> 1] = f2h(a0) | ((unsigned)f2h(a1) << 16);
                }
                uint4 lo = {pv[0], pv[1], pv[2], pv[3]};
                uint4 hi = {pv[4], pv[5], pv[6], pv[7]};
                *(uint4*)(smem + ((w * 128 + ic * 32) ^ swz)) = lo;
                *(uint4*)(smem + ((w * 128 + ic * 32 + 16) ^ swz)) = hi;
            }
        } else {
            const unsigned short* hb = hin + (size_t)b * Cn * HW + hh * 256 + w;
#pragma unroll
            for (int ic = 0; ic < 4; ++ic) {
                unsigned pv[8];
#pragma unroll
                for (int j2 = 0; j2 < 16; j2 += 2) {
                    unsigned a0 = hb[(size_t)(ic * 16 + j2) * HW];
                    unsigned a1 = hb[(size_t)(ic * 16 + j2 + 1) * HW];
                    pv[j2 >> 1] = a0 | (a1 << 16);
                }
                uint4 lo = {pv[0], pv[1], pv[2], pv[3]};
                uint4 hi = {pv[4], pv[5], pv[6], pv[7]};
                *(uint4*)(smem + ((w * 128 + ic * 32) ^ swz)) = lo;
                *(uint4*)(smem + ((w * 128 + ic * 32 + 16) ^ swz)) = hi;
            }
        }
    }
    __syncthreads();
    // MFMA: C[pix][o] = E@Y + A@pw; +bias, gelu -> packed fp16 gp
    uint2 gp[4][4];
    {
        const uint4* efr4 = (const uint4*)efr;
        const uint4* pw4  = (const uint4*)pwfr;
        const uint4* Y4 = (const uint4*)Ybuf + ((size_t)b * 256 + hh) * 256;
        float biasn[4];
        half8 ybf[4]; uint4 cwa[4], cwb[4];
#pragma unroll
        for (int nt = 0; nt < 4; ++nt) {
            int o = nt * 16 + (lane & 15);
            biasn[nt] = pwb[l * 64 + o];
            ybf[nt] = __builtin_bit_cast(half8, Y4[o * 4 + tg]);
            cwa[nt] = pw4[((l * 2 + 0) * 4 + nt) * 64 + lane];
            cwb[nt] = pw4[((l * 2 + 1) * 4 + nt) * 64 + lane];
        }
#pragma unroll
        for (int mt = 0; mt < 4; ++mt) {
            int mtA = q * 4 + mt;
            half8 ea = __builtin_bit_cast(half8, efr4[mtA * 64 + lane]);
            int row = mtA * 16 + (lane & 15);
            int rsw = (row & 7) << 4;
            half8 a0 = *(const half8*)(smem + ((row * 128 + tg * 16) ^ rsw));
            half8 a1 = *(const half8*)(smem + ((row * 128 + 64 + tg * 16) ^ rsw));
#pragma unroll
            for (int nt = 0; nt < 4; ++nt) {
                f32x4 acc = {0.f, 0.f, 0.f, 0.f};
                acc = __builtin_amdgcn_mfma_f32_16x16x32_f16(ea, ybf[nt], acc, 0, 0, 0);
                acc = __builtin_amdgcn_mfma_f32_16x16x32_f16(a0, __builtin_bit_cast(half8, cwa[nt]), acc, 0, 0, 0);
                acc = __builtin_amdgcn_mfma_f32_16x16x32_f16(a1, __builtin_bit_cast(half8, cwb[nt]), acc, 0, 0, 0);
                float g0 = gelu_exact(acc[0] + biasn[nt]);
                float g1 = gelu_exact(acc[1] + biasn[nt]);
                float g2 = gelu_exact(acc[2] + biasn[nt]);
                float g3 = gelu_exact(acc[3] + biasn[nt]);
                gp[mt][nt].x = f2h(g0) | ((unsigned)f2h(g1) << 16);
                gp[mt][nt].y = f2h(g2) | ((unsigned)f2h(g3) << 16);
            }
        }
    }
    // global h stores: fp16 packed
    unsigned short* hnb = hout + (size_t)b * Cn * HW + hh * 256;
#pragma unroll
    for (int mt = 0; mt < 4; ++mt) {
        int pbase = (q * 4 + mt) * 16 + (lane >> 4) * 4;
#pragma unroll
        for (int nt = 0; nt < 4; ++nt) {
            int o = nt * 16 + (lane & 15);
            *(uint2*)(hnb + (size_t)o * HW + pbase) = gp[mt][nt];
        }
    }
    __syncthreads();   // all A_lds reads done; hsf overlay begins
#pragma unroll
    for (int mt = 0; mt < 4; ++mt) {
        int pbase = (q * 4 + mt) * 16 + (lane >> 4) * 4;
#pragma unroll
        for (int nt = 0; nt < 4; ++nt) {
            int o = nt * 16 + (lane & 15);
            int sidx = (((pbase >> 3) ^ (o & 7)) << 3) | (pbase & 7);
            *(uint2*)(smem + o * 512 + sidx * 2) = gp[mt][nt];
        }
    }
    __syncthreads();
    // MFMA W-DFT -> Xw fp16 planar [ky][p][hh][i], pre-scaled 1/16
    {
        int arow = q * 16 + (lane & 15);
        const uint4* bt = (const uint4*)bfr;
        f32x4 ac0 = {0.f, 0.f, 0.f, 0.f};
        f32x4 ac1 = {0.f, 0.f, 0.f, 0.f};
#pragma unroll
        for (int s = 0; s < 8; ++s) {
            int abyte = (arow * 512 + s * 64 + tg * 16) ^ ((arow & 7) << 4);
            half8 af = __builtin_bit_cast(half8, *(const uint4*)(smem + abyte));
            half8 b0 = __builtin_bit_cast(half8, bt[(s * 2 + 0) * 64 + lane]);
            half8 b1 = __builtin_bit_cast(half8, bt[(s * 2 + 1) * 64 + lane]);
            ac0 = __builtin_amdgcn_mfma_f32_16x16x32_f16(af, b0, ac0, 0, 0, 0);
            ac1 = __builtin_amdgcn_mfma_f32_16x16x32_f16(af, b1, ac1, 0, 0, 0);
        }
        unsigned short* Xwb = XwOut + (size_t)b * 393216;
        int rbase = q * 16 + (lane >> 4) * 4;
#pragma unroll
        for (int n = 0; n < 2; ++n) {
            f32x4 ac = n ? ac1 : ac0;
            int col = n * 16 + (lane & 15);
            int ky = col >> 1, p = col & 1;
            if (ky < Mk) {
                uint2 pk;
                pk.x = f2h(ac[0] * 0.0625f) | ((unsigned)f2h(ac[1] * 0.0625f) << 16);
                pk.y = f2h(ac[2] * 0.0625f) | ((unsigned)f2h(ac[3] * 0.0625f) << 16);
                *(uint2*)(Xwb + ((size_t)(ky * 2 + p) * 256 + hh) * 64 + rbase) = pk;
            }
        }
    }
}

// ------- fused B (layer 3): Y from global frags; h fp16 -------
__global__ __launch_bounds__(256, 4) void k_fusedB(const unsigned short* __restrict__ hin,
        const unsigned short* __restrict__ Ybuf, const float* __restrict__ pwb,
        const float* __restrict__ fc1b, const float* __restrict__ fc2w,
        const float* __restrict__ fc2b, float* __restrict__ outp,
        const unsigned short* __restrict__ efr,
        const unsigned short* __restrict__ pwfr,
        const unsigned short* __restrict__ fc1fr) {
    __shared__ __align__(16) char smem[32768];
    int b  = blockIdx.x >> 8;
    int hh = blockIdx.x & 255;
    int w  = threadIdx.x;
    int lane = w & 63, q = w >> 6;
    int tg = (lane >> 4) & 3;
    {
        int swz = (w & 7) << 4;
        const unsigned short* hb = hin + (size_t)b * Cn * HW + hh * 256 + w;
#pragma unroll
        for (int ic = 0; ic < 4; ++ic) {
            unsigned pv[8];
#pragma unroll
            for (int j2 = 0; j2 < 16; j2 += 2) {
                unsigned a0 = hb[(size_t)(ic * 16 + j2) * HW];
                unsigned a1 = hb[(size_t)(ic * 16 + j2 + 1) * HW];
                pv[j2 >> 1] = a0 | (a1 << 16);
            }
            uint4 lo = {pv[0], pv[1], pv[2], pv[3]};
            uint4 hi = {pv[4], pv[5], pv[6], pv[7]};
            *(uint4*)(smem + ((w * 128 + ic * 32) ^ swz)) = lo;
            *(uint4*)(smem + ((w * 128 + ic * 32 + 16) ^ swz)) = hi;
        }
    }
    __syncthreads();
    // conv+spec MFMA, M=o; R packed fp16
    uint2 R2[16];
    {
        const uint4* efr4 = (const uint4*)efr;
        const uint4* pw4 = (const uint4*)pwfr;
        const uint4* Y4 = (const uint4*)Ybuf + ((size_t)b * 256 + hh) * 256;
        half8 ay  = __builtin_bit_cast(half8, Y4[(q * 16 + (lane & 15)) * 4 + tg]);
        half8 aw0 = __builtin_bit_cast(half8, pw4[((3 * 2 + 0) * 4 + q) * 64 + lane]);
        half8 aw1 = __builtin_bit_cast(half8, pw4[((3 * 2 + 1) * 4 + q) * 64 + lane]);
        int obase = q * 16 + (lane >> 4) * 4;
        float4 bias4 = *(const float4*)(pwb + 3 * 64 + obase);
#pragma unroll
        for (int nt = 0; nt < 16; ++nt) {
            half8 eb = __builtin_bit_cast(half8, efr4[nt * 64 + lane]);
            int pix = nt * 16 + (lane & 15);
            int psw = (pix & 7) << 4;
            half8 b0 = *(const half8*)(smem + ((pix * 128 + tg * 16) ^ psw));
            half8 b1 = *(const half8*)(smem + ((pix * 128 + 64 + tg * 16) ^ psw));
            f32x4 acc = {0.f, 0.f, 0.f, 0.f};
            acc = __builtin_amdgcn_mfma_f32_16x16x32_f16(ay, eb, acc, 0, 0, 0);
            acc = __builtin_amdgcn_mfma_f32_16x16x32_f16(aw0, b0, acc, 0, 0, 0);
            acc = __builtin_amdgcn_mfma_f32_16x16x32_f16(aw1, b1, acc, 0, 0, 0);
            R2[nt].x = f2h(acc[0] + bias4.x) | ((unsigned)f2h(acc[1] + bias4.y) << 16);
            R2[nt].y = f2h(acc[2] + bias4.z) | ((unsigned)f2h(acc[3] + bias4.w) << 16);
        }
    }
    __syncthreads();
    {
        int obase = q * 16 + (lane >> 4) * 4;
#pragma unroll
        for (int nt = 0; nt < 16; ++nt) {
            int pix = nt * 16 + (lane & 15);
            *(uint2*)(smem + ((pix * 128 + obase * 2) ^ ((pix & 7) << 4))) = R2[nt];
        }
    }
    __syncthreads();
    const uint4* f14 = (const uint4*)fc1fr;
    float w2v[8], fb1[8];
#pragma unroll
    for (int nt = 0; nt < 8; ++nt) {
        w2v[nt] = fc2w[nt * 16 + (lane & 15)];
        fb1[nt] = fc1b[nt * 16 + (lane & 15)];
    }
    float fb = fc2b[0];
    float* ob = outp + (size_t)b * HW + hh * 256;
#pragma unroll
    for (int mt = 0; mt < 4; ++mt) {
        int mtA = q * 4 + mt;
        int row = mtA * 16 + (lane & 15);
        int rsw = (row & 7) << 4;
        half8 a0 = *(const half8*)(smem + ((row * 128 + tg * 16) ^ rsw));
        half8 a1 = *(const half8*)(smem + ((row * 128 + 64 + tg * 16) ^ rsw));
        float s0 = 0.f, s1 = 0.f, s2 = 0.f, s3 = 0.f;
#pragma unroll
        for (int nt = 0; nt < 8; ++nt) {
            f32x4 acc = {0.f, 0.f, 0.f, 0.f};
            acc = __builtin_amdgcn_mfma_f32_16x16x32_f16(a0, __builtin_bit_cast(half8, f14[(0 * 8 + nt) * 64 + lane]), acc, 0, 0, 0);
            acc = __builtin_amdgcn_mfma_f32_16x16x32_f16(a1, __builtin_bit_cast(half8, f14[(1 * 8 + nt) * 64 + lane]), acc, 0, 0, 0);
            s0 += gelu_exact(acc[0] + fb1[nt]) * w2v[nt];
            s1 += gelu_exact(acc[1] + fb1[nt]) * w2v[nt];
            s2 += gelu_exact(acc[2] + fb1[nt]) * w2v[nt];
            s3 += gelu_exact(acc[3] + fb1[nt]) * w2v[nt];
        }
#pragma unroll
        for (int msk = 1; msk <= 8; msk <<= 1) {
            s0 += __shfl_xor(s0, msk);
            s1 += __shfl_xor(s1, msk);
            s2 += __shfl_xor(s2, msk);
            s3 += __shfl_xor(s3, msk);
        }
        int cc = lane & 15;
        if (cc < 4) {
            float v = (cc == 0) ? s0 : (cc == 1) ? s1 : (cc == 2) ? s2 : s3;
            ob[mtA * 16 + (lane >> 4) * 4 + cc] = v + fb;
        }
    }
}

extern "C" void kernel_launch(void* const* d_in, const int* in_sizes, int n_in,
                              void* d_out, int out_size, void* d_ws, size_t ws_size,
                              hipStream_t stream) {
    const float* x    = (const float*)d_in[0];
    const float* fc0w = (const float*)d_in[1];
    const float* fc0b = (const float*)d_in[2];
    const float* scw  = (const float*)d_in[3];
    const float* pww  = (const float*)d_in[4];
    const float* pwb  = (const float*)d_in[5];
    const float* fc1w = (const float*)d_in[6];
    const float* fc1b = (const float*)d_in[7];
    const float* fc2w = (const float*)d_in[8];
    const float* fc2b = (const float*)d_in[9];
    float* out = (float*)d_out;
    float* ws  = (float*)d_ws;

    // base floats: 51200 tables/frags + wfr 9,437,184 + Xxw 98,304 = 9,586,688
    // per batch: h16 2,097,152 + Xw16 196,608 + Z 36,864 + Xf 36,864
    //          + Ybuf 262,144 = 2,629,632
    const size_t basef = 9586688;
    const size_t perbf = 2629632;
    int bc = 0;
    for (int cand = 16; cand >= 1; cand >>= 1)
        if ((basef + perbf * (size_t)cand) * 4 <= ws_size) { bc = cand; break; }
    if (bc == 0) return;

    float* tabc = ws;
    float* tabs = tabc + 256;
    float* twc  = tabs + 256;
    float* tws_ = twc + 3072;
    float* tcs  = tws_ + 3072;
    float* bfr  = tcs + 512;            // fp16[8192]
    float* tfr  = bfr + 4096;           // fp16[12288]
    float* yfrA = tfr + 6144;           // fp16[16384]
    float* efr  = yfrA + 8192;          // fp16[8192]
    float* pwfr = efr + 4096;           // fp16[16384]
    float* fc1f = pwfr + 8192;          // fp16[8192]
    float* Xfx  = fc1f + 4096;          // 9216
    float* wfr  = Xfx + 9216;           // fp16[18,874,368]
    float* Xxw  = wfr + 9437184;        // 98,304 fp32 (prologue only)
    float* hbuf = ws + basef;
    unsigned short* h16  = (unsigned short*)hbuf;
    unsigned short* Xw16 = (unsigned short*)(hbuf + (size_t)bc * 2097152);
    float* Zb   = hbuf + (size_t)bc * (2097152 + 196608);
    float* Xf2  = Zb + (size_t)bc * 36864;
    unsigned short* Ybuf = (unsigned short*)(Xf2 + (size_t)bc * 36864);

    k_init_tables<<<1, 256, 0, stream>>>(tabc, tabs, twc, tws_, tcs,
                                         (unsigned short*)bfr,
                                         (unsigned short*)tfr,
                                         (unsigned short*)yfrA);
    k_prep_frag<<<128, 256, 0, stream>>>(pww, fc1w,
                                         (unsigned short*)efr,
                                         (unsigned short*)pwfr,
                                         (unsigned short*)fc1f);
    k_prep_wfrag<<<1152, 256, 0, stream>>>(scw, (unsigned short*)wfr);
    k_dftw_x<<<64, 64, 0, stream>>>(x, Xxw, twc, tws_);
    k_xdfth<<<18, 256, 0, stream>>>(Xxw, Xfx, tabc, tabs);

    for (int b0 = 0; b0 < 16; b0 += bc) {
        k_mixZ2<<<576, 256, 0, stream>>>(Xfx, (const unsigned short*)wfr,
                                         fc0w, fc0b, Zb, 0, 1, b0, bc);
        k_prepY<<<bc * 12, 256, 0, stream>>>(Zb, (const unsigned short*)yfrA, Ybuf);
        k_fusedA<<<bc * 256, 256, 0, stream>>>(x + (size_t)b0 * HW, h16, Ybuf, pwb,
                                               fc0w, fc0b, h16, Xw16,
                                               (const unsigned short*)bfr,
                                               (const unsigned short*)efr,
                                               (const unsigned short*)pwfr, 0, 1);
        for (int l = 1; l <= 2; ++l) {
            k_dfth<<<bc * 12, 256, 0, stream>>>(Xw16, Xf2, (const unsigned short*)tfr);
            k_mixZ2<<<576, 256, 0, stream>>>(Xf2, (const unsigned short*)wfr,
                                             fc0w, fc0b, Zb, l, 0, b0, bc);
            k_prepY<<<bc * 12, 256, 0, stream>>>(Zb, (const unsigned short*)yfrA, Ybuf);
            k_fusedA<<<bc * 256, 256, 0, stream>>>(x, h16, Ybuf, pwb,
                                                   fc0w, fc0b, h16, Xw16,
                                                   (const unsigned short*)bfr,
                                                   (const unsigned short*)efr,
                                                   (const unsigned short*)pwfr, l, 0);
        }
        k_dfth<<<bc * 12, 256, 0, stream>>>(Xw16, Xf2, (const unsigned short*)tfr);
        k_mixZ2<<<576, 256, 0, stream>>>(Xf2, (const unsigned short*)wfr,
                                         fc0w, fc0b, Zb, 3, 0, b0, bc);
        k_prepY<<<bc * 12, 256, 0, stream>>>(Zb, (const unsigned short*)yfrA, Ybuf);
        k_fusedB<<<bc * 256, 256, 0, stream>>>(h16, Ybuf, pwb, fc1b, fc2w, fc2b,
                                               out + (size_t)b0 * HW,
                                               (const unsigned short*)efr,
                                               (const unsigned short*)pwfr,
                                               (const unsigned short*)fc1f);
    }
}